// Round 4
// baseline (406.823 us; speedup 1.0000x reference)
//
#include <hip/hip_runtime.h>

// ---------------------------------------------------------------------------
// DualGCN v6: chunk-phased SpMM for L2 locality.
//   - bucket_sort_kernel: ballot-rank bucket of each row's (col,val) by
//     2048-col chunk (half-wave per row, ~25 ballots, no bitonic).
//   - spmm_chunked: all blocks co-resident (4 row-tiles/block, full grid
//     residency); outer loop over 25 col-chunks with per-row cursors and
//     register accumulators + block barrier per phase. At any instant the
//     gather working set is ~1-2 chunks (~1-2 MB) -> fits XCD L2 ->
//     L2-miss traffic drops toward compulsory.
//   - GEMMs / structure unchanged from v5 (verified).
// N=50000, E=800000, H=128, OUT=64.
// ---------------------------------------------------------------------------

typedef short short8 __attribute__((ext_vector_type(8)));
typedef float floatx4 __attribute__((ext_vector_type(4)));

#define CHUNK_SHIFT 11          // 2048 cols per chunk = 512 KB of 128-wide X
#define NCHUNK 25               // ceil(50000 / 2048)

__device__ inline unsigned short f2bf(float f) {
  unsigned u = __builtin_bit_cast(unsigned, f);
  u += 0x7fffu + ((u >> 16) & 1u);      // round-to-nearest-even
  return (unsigned short)(u >> 16);
}
__device__ inline unsigned pack2(float a, float b) {
  return (unsigned)f2bf(a) | ((unsigned)f2bf(b) << 16);
}
__device__ inline float bf_lo(unsigned w) {
  return __builtin_bit_cast(float, w << 16);
}
__device__ inline float bf_hi(unsigned w) {
  return __builtin_bit_cast(float, w & 0xffff0000u);
}

// y=0: rowptr for graph a; y=1: rowptr for graph b; y=2: convert weights.
// Wo de-interleaved into Wo0 = Wo[:, :128] and Wo1 = Wo[:, 128:].
__global__ __launch_bounds__(256) void setup_kernel(
    const int* __restrict__ rowA, const int* __restrict__ rowB,
    int E, int n, int* __restrict__ rpa, int* __restrict__ rpb,
    const float* __restrict__ Wa0, const float* __restrict__ Wa1,
    const float* __restrict__ Wb0, const float* __restrict__ Wb1,
    const float* __restrict__ Wm,  const float* __restrict__ Wo,
    unsigned short* __restrict__ Wout)
{
  if (blockIdx.y == 2) {
    for (int i = blockIdx.x * 256 + threadIdx.x; i < 131072; i += gridDim.x * 256) {
      float v;
      if      (i < 16384)  v = Wa0[i];
      else if (i < 32768)  v = Wa1[i - 16384];
      else if (i < 49152)  v = Wb0[i - 32768];
      else if (i < 65536)  v = Wb1[i - 49152];
      else if (i < 114688) v = Wm[i - 65536];
      else {
        int o = i - 114688;           // [0, 16384)
        int half = o >> 13;           // 0 -> Wo0, 1 -> Wo1
        int idx = o & 8191;
        int r = idx >> 7, c = idx & 127;
        v = Wo[r * 256 + half * 128 + c];
      }
      Wout[i] = f2bf(v);
    }
    return;
  }
  int i = blockIdx.x * blockDim.x + threadIdx.x;
  if (i > n) return;
  const int* row = blockIdx.y ? rowB : rowA;
  int* rp = blockIdx.y ? rpb : rpa;
  int lo = 0, hi = E;
  while (lo < hi) {
    int mid = (lo + hi) >> 1;
    if (row[mid] < i) lo = mid + 1; else hi = mid;
  }
  rp[i] = lo;
}

// Bucket each row's (col,val) pairs by col-chunk (stable within chunk).
// Half-wave (32 lanes) per row; ballot-rank, no bitonic. deg>32 rows (prob
// ~1e-4) fall back to an unsorted copy (SpMM stays correct, loses locality).
__global__ __launch_bounds__(256) void bucket_sort_kernel(
    const int* __restrict__ rpa, const int* __restrict__ rpb,
    const int* __restrict__ colA, const float* __restrict__ valA,
    const int* __restrict__ colB, const float* __restrict__ valB,
    int* __restrict__ colA2, float* __restrict__ valA2,
    int* __restrict__ colB2, float* __restrict__ valB2, int n)
{
  int r = blockIdx.x * 8 + ((int)threadIdx.x >> 5);
  if (r >= n) return;
  const int*   rp   = blockIdx.y ? rpb  : rpa;
  const int*   col  = blockIdx.y ? colB : colA;
  const float* val  = blockIdx.y ? valB : valA;
  int*   col2 = blockIdx.y ? colB2 : colA2;
  float* val2 = blockIdx.y ? valB2 : valA2;

  const int half = ((int)threadIdx.x >> 5) & 1;
  const int l2   = threadIdx.x & 31;
  int e0 = rp[r], e1 = rp[r + 1];
  int deg = e1 - e0;
  if (deg > 32) {                     // rare fallback: unsorted copy
    for (int e = e0 + l2; e < e1; e += 32) { col2[e] = col[e]; val2[e] = val[e]; }
    return;
  }
  int c = 0; float v = 0.f; int ch = 64;
  if (l2 < deg) { c = col[e0 + l2]; v = val[e0 + l2]; ch = c >> CHUNK_SHIFT; }
  int base = 0, rank = 0;
  for (int cc = 0; cc < NCHUNK; ++cc) {
    unsigned long long m64 = __ballot(ch == cc);
    unsigned mm = (unsigned)(m64 >> (half * 32));
    if (cc < ch)  base += __popc(mm);
    if (cc == ch) rank  = __popc(mm & ((1u << l2) - 1u));
  }
  if (l2 < deg) {
    int dst = e0 + base + rank;
    col2[dst] = c; val2[dst] = v;
  }
}

// ---------------------------------------------------------------------------
// Chunk-phased SpMM: Y[r,:] = sum_e val[e] * X[col[e],:]
// WIDTH/8 lanes per row; TPB row-tiles per block (accumulators + cursors in
// registers, statically unrolled). Outer loop over NCHUNK col-chunks; edges
// are chunk-bucketed so each phase touches only one 512 KB slice of X.
// __syncthreads per phase keeps the block's waves aligned; full grid
// residency keeps blocks aligned.
// ---------------------------------------------------------------------------
template <int WIDTH, int TPB, bool OUTF32>
__device__ __forceinline__ void spmm_chunked(
    const int* __restrict__ rowptr, const int* __restrict__ col,
    const float* __restrict__ val, const unsigned short* __restrict__ X,
    void* __restrict__ Yv, int n, int bx)
{
  constexpr int LPR = WIDTH / 8;        // lanes per row
  constexpr int GPB = 256 / LPR;        // row-groups per tile
  const int grp  = (int)threadIdx.x / LPR;
  const int lane = threadIdx.x & (LPR - 1);
  const size_t loff = (size_t)lane * 8;

  int   e_[TPB], e1_[TPB], c_[TPB], r_[TPB];
  float ac[TPB][8];
#pragma unroll
  for (int t = 0; t < TPB; ++t) {
    int r = (bx * TPB + t) * GPB + grp;
    r_[t] = r;
    if (r < n) { e_[t] = rowptr[r]; e1_[t] = rowptr[r + 1]; }
    else       { e_[t] = 0;         e1_[t] = 0; }
    c_[t] = (e_[t] < e1_[t]) ? col[e_[t]] : 0x7fffffff;
#pragma unroll
    for (int k = 0; k < 8; ++k) ac[t][k] = 0.f;
  }

  for (int ch = 0; ch < NCHUNK; ++ch) {
    const int bound = (ch + 1) << CHUNK_SHIFT;   // last bound 51200 > max col
#pragma unroll
    for (int t = 0; t < TPB; ++t) {
      int e = e_[t], e1 = e1_[t], c = c_[t];
      while (c < bound) {
        float v = val[e];
        const uint4 w = *(const uint4*)(X + (size_t)c * WIDTH + loff);
        ac[t][0] = fmaf(v, bf_lo(w.x), ac[t][0]);
        ac[t][1] = fmaf(v, bf_hi(w.x), ac[t][1]);
        ac[t][2] = fmaf(v, bf_lo(w.y), ac[t][2]);
        ac[t][3] = fmaf(v, bf_hi(w.y), ac[t][3]);
        ac[t][4] = fmaf(v, bf_lo(w.z), ac[t][4]);
        ac[t][5] = fmaf(v, bf_hi(w.z), ac[t][5]);
        ac[t][6] = fmaf(v, bf_lo(w.w), ac[t][6]);
        ac[t][7] = fmaf(v, bf_hi(w.w), ac[t][7]);
        ++e;
        c = (e < e1) ? col[e] : 0x7fffffff;
      }
      e_[t] = e; c_[t] = c;
    }
    __syncthreads();
  }

#pragma unroll
  for (int t = 0; t < TPB; ++t) {
    if (r_[t] >= n) continue;
    if (OUTF32) {
      float* Y = (float*)Yv;
      float4 o0; o0.x = ac[t][0]; o0.y = ac[t][1]; o0.z = ac[t][2]; o0.w = ac[t][3];
      float4 o1; o1.x = ac[t][4]; o1.y = ac[t][5]; o1.z = ac[t][6]; o1.w = ac[t][7];
      *(float4*)(Y + (size_t)r_[t] * WIDTH + lane * 8) = o0;
      *(float4*)(Y + (size_t)r_[t] * WIDTH + lane * 8 + 4) = o1;
    } else {
      uint4 o;
      o.x = pack2(ac[t][0], ac[t][1]); o.y = pack2(ac[t][2], ac[t][3]);
      o.z = pack2(ac[t][4], ac[t][5]); o.w = pack2(ac[t][6], ac[t][7]);
      *(uint4*)((unsigned short*)Yv + (size_t)r_[t] * WIDTH + loff) = o;
    }
  }
}

// y=0: graph a, Xa->Ya; y=1: graph b, Xb->Yb (both 128-wide, bf16 out)
// grid.x covers 64 rows/block.
__global__ __launch_bounds__(256) void spmm_dual128_kernel(
    const int* __restrict__ rpa, const int* __restrict__ cola,
    const float* __restrict__ vala, const unsigned short* __restrict__ Xa,
    unsigned short* __restrict__ Ya,
    const int* __restrict__ rpb, const int* __restrict__ colb,
    const float* __restrict__ valb, const unsigned short* __restrict__ Xb,
    unsigned short* __restrict__ Yb, int n)
{
  if (blockIdx.y == 0)
    spmm_chunked<128, 4, false>(rpa, cola, vala, Xa, Ya, n, blockIdx.x);
  else
    spmm_chunked<128, 4, false>(rpb, colb, valb, Xb, Yb, n, blockIdx.x);
}

// y=0: graph b 128-wide D->Yb (bf16, TPB=4); y=1: graph a 64-wide Q->Pout
// (f32, TPB=2). Both cover 64 rows/block -> same grid.x.
__global__ __launch_bounds__(256) void spmm_mixed_kernel(
    const int* __restrict__ rpb, const int* __restrict__ colb,
    const float* __restrict__ valb, const unsigned short* __restrict__ D,
    unsigned short* __restrict__ Yb,
    const int* __restrict__ rpa, const int* __restrict__ cola,
    const float* __restrict__ vala, const unsigned short* __restrict__ Q,
    float* __restrict__ Pout, int n)
{
  if (blockIdx.y == 0)
    spmm_chunked<128, 4, false>(rpb, colb, valb, D, Yb, n, blockIdx.x);
  else
    spmm_chunked<64, 2, true>(rpa, cola, vala, Q, Pout, n, blockIdx.x);
}

// ---------------------------------------------------------------------------
// GEMM building blocks (unchanged from v3/v5).
// ---------------------------------------------------------------------------
#define LDXP 136   // padded LDS row stride (bf16 units)

__device__ inline void stage_bf16(const unsigned short* __restrict__ Xp,
                                  unsigned short* Xs, int row0, int n,
                                  int rloc, int c8)
{
#pragma unroll
  for (int p = 0; p < 8; ++p) {
    int r = p * 16 + rloc;
    int gr = row0 + r;
    uint4 v = make_uint4(0u, 0u, 0u, 0u);
    if (gr < n) v = *(const uint4*)(Xp + (size_t)gr * 128 + c8);
    *(uint4*)(Xs + r * LDXP + c8) = v;
  }
}

template <int NT>
__device__ inline void mfma_phase(const unsigned short* __restrict__ W, int Kstride,
                                  int kc, const unsigned short* Xs,
                                  int wm, int wn, int l15, int quad,
                                  floatx4 (&acc)[4][NT])
{
#pragma unroll
  for (int k0 = 0; k0 < 128; k0 += 32) {
    const int ko = k0 + quad * 8;
    short8 aW[NT], bX[4];
#pragma unroll
    for (int j = 0; j < NT; ++j)
      aW[j] = *(const short8*)(W + (size_t)(wn * (16 * NT) + j * 16 + l15) * Kstride + kc + ko);
#pragma unroll
    for (int i = 0; i < 4; ++i)
      bX[i] = *(const short8*)(Xs + (wm * 64 + i * 16 + l15) * LDXP + ko);
#pragma unroll
    for (int i = 0; i < 4; ++i)
#pragma unroll
      for (int j = 0; j < NT; ++j)
        acc[i][j] = __builtin_amdgcn_mfma_f32_16x16x32_bf16(aW[j], bX[i], acc[i][j], 0, 0, 0);
  }
}

// Y = (relu?)(X @ W.T + b [+ add]), X = up to 3 bf16 slabs (free concat).
template <int K, int HOUT, bool RELU, bool OUTBF, bool ADDEND>
__global__ __launch_bounds__(256, 2) void gemm_std_kernel(
    const unsigned short* __restrict__ X0, const unsigned short* __restrict__ X1,
    const unsigned short* __restrict__ X2, const unsigned short* __restrict__ W,
    const float* __restrict__ b, const float* __restrict__ add,
    void* __restrict__ Yv, int n)
{
  constexpr int NT = HOUT / 32;
  __shared__ unsigned short Xs[128 * LDXP];
  const int tid = threadIdx.x;
  const int lane = tid & 63;
  const int wave = tid >> 6;
  const int wm = wave >> 1;
  const int wn = wave & 1;
  const int l15 = lane & 15;
  const int quad = lane >> 4;
  const int row0 = blockIdx.x * 128;
  const int c8 = (tid & 15) * 8;
  const int rloc = tid >> 4;

  floatx4 acc[4][NT];
#pragma unroll
  for (int i = 0; i < 4; ++i)
#pragma unroll
    for (int j = 0; j < NT; ++j) acc[i][j] = (floatx4){0.f, 0.f, 0.f, 0.f};

  for (int kc = 0; kc < K; kc += 128) {
    const unsigned short* Xp = (kc == 0) ? X0 : (kc == 128) ? X1 : X2;
    if (kc) __syncthreads();
    stage_bf16(Xp, Xs, row0, n, rloc, c8);
    __syncthreads();
    mfma_phase<NT>(W, K, kc, Xs, wm, wn, l15, quad, acc);
  }

#pragma unroll
  for (int i = 0; i < 4; ++i) {
    int r = row0 + wm * 64 + i * 16 + l15;
    if (r >= n) continue;
#pragma unroll
    for (int j = 0; j < NT; ++j) {
      int c0 = wn * (16 * NT) + j * 16 + quad * 4;
      float4 bb = *(const float4*)(b + c0);
      float v0 = acc[i][j][0] + bb.x;
      float v1 = acc[i][j][1] + bb.y;
      float v2 = acc[i][j][2] + bb.z;
      float v3 = acc[i][j][3] + bb.w;
      if (ADDEND) {
        float4 ad = *(const float4*)(add + (size_t)r * HOUT + c0);
        v0 += ad.x; v1 += ad.y; v2 += ad.z; v3 += ad.w;
      }
      if (RELU) {
        v0 = fmaxf(v0, 0.f); v1 = fmaxf(v1, 0.f);
        v2 = fmaxf(v2, 0.f); v3 = fmaxf(v3, 0.f);
      }
      if (OUTBF) {
        uint2 o; o.x = pack2(v0, v1); o.y = pack2(v2, v3);
        *(uint2*)((unsigned short*)Yv + (size_t)r * HOUT + c0) = o;
      } else {
        float4 o; o.x = v0; o.y = v1; o.z = v2; o.w = v3;
        *(float4*)((float*)Yv + (size_t)r * HOUT + c0) = o;
      }
    }
  }
}

// A = relu(x@W1.T+b1), C = relu(x@W2.T+b2) from fp32 x, shared X staging.
__global__ __launch_bounds__(256, 2) void gemm_dual_f32_kernel(
    const float* __restrict__ X, const unsigned short* __restrict__ W1,
    const unsigned short* __restrict__ W2, const float* __restrict__ b1,
    const float* __restrict__ b2, unsigned short* __restrict__ Y1,
    unsigned short* __restrict__ Y2, int n)
{
  constexpr int NT = 4;  // HOUT = 128
  __shared__ unsigned short Xs[128 * LDXP];
  const int tid = threadIdx.x;
  const int lane = tid & 63;
  const int wave = tid >> 6;
  const int wm = wave >> 1;
  const int wn = wave & 1;
  const int l15 = lane & 15;
  const int quad = lane >> 4;
  const int row0 = blockIdx.x * 128;
  const int c8 = (tid & 15) * 8;
  const int rloc = tid >> 4;

#pragma unroll
  for (int p = 0; p < 8; ++p) {
    int r = p * 16 + rloc;
    int gr = row0 + r;
    uint4 o = make_uint4(0u, 0u, 0u, 0u);
    if (gr < n) {
      float4 f0 = *(const float4*)(X + (size_t)gr * 128 + c8);
      float4 f1 = *(const float4*)(X + (size_t)gr * 128 + c8 + 4);
      o.x = pack2(f0.x, f0.y); o.y = pack2(f0.z, f0.w);
      o.z = pack2(f1.x, f1.y); o.w = pack2(f1.z, f1.w);
    }
    *(uint4*)(Xs + r * LDXP + c8) = o;
  }
  __syncthreads();

  for (int s = 0; s < 2; ++s) {
    const unsigned short* W = s ? W2 : W1;
    const float* b = s ? b2 : b1;
    unsigned short* Y = s ? Y2 : Y1;
    floatx4 acc[4][NT];
#pragma unroll
    for (int i = 0; i < 4; ++i)
#pragma unroll
      for (int j = 0; j < NT; ++j) acc[i][j] = (floatx4){0.f, 0.f, 0.f, 0.f};
    mfma_phase<NT>(W, 128, 0, Xs, wm, wn, l15, quad, acc);
#pragma unroll
    for (int i = 0; i < 4; ++i) {
      int r = row0 + wm * 64 + i * 16 + l15;
      if (r >= n) continue;
#pragma unroll
      for (int j = 0; j < NT; ++j) {
        int c0 = wn * 64 + j * 16 + quad * 4;
        float4 bb = *(const float4*)(b + c0);
        float v0 = fmaxf(acc[i][j][0] + bb.x, 0.f);
        float v1 = fmaxf(acc[i][j][1] + bb.y, 0.f);
        float v2 = fmaxf(acc[i][j][2] + bb.z, 0.f);
        float v3 = fmaxf(acc[i][j][3] + bb.w, 0.f);
        uint2 o; o.x = pack2(v0, v1); o.y = pack2(v2, v3);
        *(uint2*)(Y + (size_t)r * 128 + c0) = o;
      }
    }
  }
}

// Q = (relu(B@Wa1.T + ba1)) @ Wo0.T  — two chained MFMA stages through LDS;
// the intermediate A2 never touches global memory.
__global__ __launch_bounds__(256, 2) void gemm_chain_kernel(
    const unsigned short* __restrict__ X, const unsigned short* __restrict__ W1,
    const float* __restrict__ b1, const unsigned short* __restrict__ W2,
    unsigned short* __restrict__ Q, int n)
{
  __shared__ unsigned short Xs[128 * LDXP];
  const int tid = threadIdx.x;
  const int lane = tid & 63;
  const int wave = tid >> 6;
  const int wm = wave >> 1;
  const int wn = wave & 1;
  const int l15 = lane & 15;
  const int quad = lane >> 4;
  const int row0 = blockIdx.x * 128;
  const int c8 = (tid & 15) * 8;
  const int rloc = tid >> 4;

  stage_bf16(X, Xs, row0, n, rloc, c8);
  __syncthreads();

  // stage 1: A2 = relu(B @ Wa1.T + ba1), HOUT=128
  floatx4 acc1[4][4];
#pragma unroll
  for (int i = 0; i < 4; ++i)
#pragma unroll
    for (int j = 0; j < 4; ++j) acc1[i][j] = (floatx4){0.f, 0.f, 0.f, 0.f};
  mfma_phase<4>(W1, 128, 0, Xs, wm, wn, l15, quad, acc1);
  __syncthreads();   // all stage-1 reads of Xs done before overwrite

  // bias+relu, pack bf16, write A2 tile back into Xs
#pragma unroll
  for (int i = 0; i < 4; ++i) {
    int r2 = wm * 64 + i * 16 + l15;
#pragma unroll
    for (int j = 0; j < 4; ++j) {
      int c2 = wn * 64 + j * 16 + quad * 4;
      float4 bb = *(const float4*)(b1 + c2);
      float v0 = fmaxf(acc1[i][j][0] + bb.x, 0.f);
      float v1 = fmaxf(acc1[i][j][1] + bb.y, 0.f);
      float v2 = fmaxf(acc1[i][j][2] + bb.z, 0.f);
      float v3 = fmaxf(acc1[i][j][3] + bb.w, 0.f);
      uint2 o; o.x = pack2(v0, v1); o.y = pack2(v2, v3);
      *(uint2*)(Xs + r2 * LDXP + c2) = o;
    }
  }
  __syncthreads();

  // stage 2: Q = A2 @ Wo0.T, HOUT=64 (pure, no bias)
  floatx4 acc2[4][2];
#pragma unroll
  for (int i = 0; i < 4; ++i)
#pragma unroll
    for (int j = 0; j < 2; ++j) acc2[i][j] = (floatx4){0.f, 0.f, 0.f, 0.f};
  mfma_phase<2>(W2, 128, 0, Xs, wm, wn, l15, quad, acc2);

#pragma unroll
  for (int i = 0; i < 4; ++i) {
    int r = row0 + wm * 64 + i * 16 + l15;
    if (r >= n) continue;
#pragma unroll
    for (int j = 0; j < 2; ++j) {
      int c0 = wn * 32 + j * 16 + quad * 4;
      uint2 o;
      o.x = pack2(acc2[i][j][0], acc2[i][j][1]);
      o.y = pack2(acc2[i][j][2], acc2[i][j][3]);
      *(uint2*)(Q + (size_t)r * 64 + c0) = o;
    }
  }
}

extern "C" void kernel_launch(void* const* d_in, const int* in_sizes, int n_in,
                              void* d_out, int out_size, void* d_ws, size_t ws_size,
                              hipStream_t stream)
{
  const float* x     = (const float*)d_in[0];
  const int*   row_a = (const int*)d_in[1];
  const int*   col_a = (const int*)d_in[2];
  const float* val_a = (const float*)d_in[3];
  const int*   row_b = (const int*)d_in[4];
  const int*   col_b = (const int*)d_in[5];
  const float* val_b = (const float*)d_in[6];
  const float* Wa0 = (const float*)d_in[7];  const float* ba0 = (const float*)d_in[8];
  const float* Wa1 = (const float*)d_in[9];  const float* ba1 = (const float*)d_in[10];
  const float* Wb0 = (const float*)d_in[11]; const float* bb0 = (const float*)d_in[12];
  const float* Wb1 = (const float*)d_in[13]; const float* bb1 = (const float*)d_in[14];
  const float* Wm  = (const float*)d_in[15]; const float* bm  = (const float*)d_in[16];
  const float* Wo  = (const float*)d_in[17]; const float* bo  = (const float*)d_in[18];
  float* out = (float*)d_out;

  const int n = in_sizes[0] / 128;   // 50000
  const int E = in_sizes[1];         // 800000

  char* ws = (char*)d_ws;
  size_t off = 0;
  auto alloc = [&](size_t bytes) {
    void* p = ws + off;
    off = (off + bytes + 255) & ~(size_t)255;
    return p;
  };
  int* rpa = (int*)alloc((size_t)(n + 1) * sizeof(int));
  int* rpb = (int*)alloc((size_t)(n + 1) * sizeof(int));
  unsigned short* Wcat = (unsigned short*)alloc(131072 * sizeof(unsigned short));
  int*   col2a = (int*)alloc((size_t)E * sizeof(int));
  float* val2a = (float*)alloc((size_t)E * sizeof(float));
  int*   col2b = (int*)alloc((size_t)E * sizeof(int));
  float* val2b = (float*)alloc((size_t)E * sizeof(float));
  const size_t slab = (size_t)n * 128 * sizeof(unsigned short);
  unsigned short* A  = (unsigned short*)alloc(slab);   // branch-a hidden
  unsigned short* C  = (unsigned short*)alloc(slab);   // g0
  unsigned short* B  = (unsigned short*)alloc(slab);   // graph-a sp1 out / g2
  unsigned short* B2 = (unsigned short*)alloc(slab);   // graph-b sp1 out
  unsigned short* D  = (unsigned short*)alloc(slab);   // g1
  unsigned short* A3 = (unsigned short*)alloc(slab);   // x_b
  unsigned short* Q  = (unsigned short*)alloc((size_t)n * 64 * sizeof(unsigned short));
  float* Pout = (float*)alloc((size_t)n * 64 * sizeof(float)); // x_a @ Wo0^T

  const unsigned short* Wa0b = Wcat;
  const unsigned short* Wa1b = Wcat + 16384;
  const unsigned short* Wb0b = Wcat + 32768;
  const unsigned short* Wb1b = Wcat + 49152;
  const unsigned short* Wmb  = Wcat + 65536;
  const unsigned short* Wo0b = Wcat + 114688;
  const unsigned short* Wo1b = Wcat + 122880;

  dim3 blk(256);
  dim3 g_setup((n + 1 + 255) / 256, 3);
  dim3 g_sort((n + 7) / 8, 2);
  dim3 g_lin((n + 127) / 128);
  dim3 g_sp2((n + 63) / 64, 2);      // 64 rows per block for all spmm variants

  setup_kernel<<<g_setup, blk, 0, stream>>>(row_a, row_b, E, n, rpa, rpb,
                                            Wa0, Wa1, Wb0, Wb1, Wm, Wo, Wcat);
  bucket_sort_kernel<<<g_sort, blk, 0, stream>>>(rpa, rpb, col_a, val_a,
                                                 col_b, val_b, col2a, val2a,
                                                 col2b, val2b, n);

  // A = relu(x Wa0^T + ba0), C = relu(x Wb0^T + bb0)   (shared x staging)
  gemm_dual_f32_kernel<<<g_lin, blk, 0, stream>>>(x, Wa0b, Wb0b, ba0, bb0, A, C, n);

  // independent first SpMMs of both branches in one launch
  spmm_dual128_kernel<<<g_sp2, blk, 0, stream>>>(
      rpa, col2a, val2a, A, B,      // graph a: A -> B
      rpb, col2b, val2b, C, B2, n); // graph b: C -> B2

  // branch a commuted tail stage 1: Q = relu(B Wa1^T + ba1) Wo0^T
  gemm_chain_kernel<<<g_lin, blk, 0, stream>>>(B, Wa1b, ba1, Wo0b, Q, n);
  // branch b: g1 = relu(B2 Wb1^T + bb1)
  gemm_std_kernel<128, 128, true, true, false><<<g_lin, blk, 0, stream>>>(
      B2, nullptr, nullptr, Wb1b, bb1, nullptr, D, n);

  // independent tail SpMMs in one launch: g2 = spmm_b(D), Pout = spmm_a(Q)
  spmm_mixed_kernel<<<g_sp2, blk, 0, stream>>>(
      rpb, col2b, val2b, D, B,      // graph b: D -> B (g2)
      rpa, col2a, val2a, Q, Pout, n);

  // x_b = relu([g0,g1,g2] Wm^T + bm)
  gemm_std_kernel<384, 128, true, true, false><<<g_lin, blk, 0, stream>>>(
      C, D, B, Wmb, bm, nullptr, A3, n);

  // out = x_b Wo1^T + bo + Pout   (fp32 out)
  gemm_std_kernel<128, 64, false, false, true><<<g_lin, blk, 0, stream>>>(
      A3, nullptr, nullptr, Wo1b, bo, Pout, out, n);
}

// Round 5
// 337.923 us; speedup vs baseline: 1.2039x; 1.2039x over previous
//
#include <hip/hip_runtime.h>

// ---------------------------------------------------------------------------
// DualGCN v7: v5 streaming SpMM (proven) + K-split Wm GEMM overlapped with
// the SpMM launches.
//   x_b = relu(g0 Wm0^T + g1 Wm1^T + g2 Wm2^T + bm) is split K-wise:
//     P1 = g0 Wm0^T + bm   -> merged into SpMM-1 launch (blockIdx.y==2)
//     P2 = P1 + g1 Wm1^T   -> merged into SpMM-2 launch (blockIdx.y==2)
//     A3 = relu(P2 + g2 Wm2^T)  (K=128, only 1/3 on the critical path)
//   GEMM blocks (MFMA-bound) co-schedule with SpMM blocks (memory-starved,
//   VALUBusy 33%) on complementary pipes.
//   chain GEMM + g1 GEMM merged into one launch (independent).
// N=50000, E=800000, H=128, OUT=64.
// ---------------------------------------------------------------------------

typedef short short8 __attribute__((ext_vector_type(8)));
typedef float floatx4 __attribute__((ext_vector_type(4)));

__device__ inline unsigned short f2bf(float f) {
  unsigned u = __builtin_bit_cast(unsigned, f);
  u += 0x7fffu + ((u >> 16) & 1u);      // round-to-nearest-even
  return (unsigned short)(u >> 16);
}
__device__ inline unsigned pack2(float a, float b) {
  return (unsigned)f2bf(a) | ((unsigned)f2bf(b) << 16);
}
__device__ inline float bf_lo(unsigned w) {
  return __builtin_bit_cast(float, w << 16);
}
__device__ inline float bf_hi(unsigned w) {
  return __builtin_bit_cast(float, w & 0xffff0000u);
}

// y=0: rowptr for graph a; y=1: rowptr for graph b; y=2: convert weights.
// Wo de-interleaved into Wo0 = Wo[:, :128] and Wo1 = Wo[:, 128:].
__global__ __launch_bounds__(256) void setup_kernel(
    const int* __restrict__ rowA, const int* __restrict__ rowB,
    int E, int n, int* __restrict__ rpa, int* __restrict__ rpb,
    const float* __restrict__ Wa0, const float* __restrict__ Wa1,
    const float* __restrict__ Wb0, const float* __restrict__ Wb1,
    const float* __restrict__ Wm,  const float* __restrict__ Wo,
    unsigned short* __restrict__ Wout)
{
  if (blockIdx.y == 2) {
    for (int i = blockIdx.x * 256 + threadIdx.x; i < 131072; i += gridDim.x * 256) {
      float v;
      if      (i < 16384)  v = Wa0[i];
      else if (i < 32768)  v = Wa1[i - 16384];
      else if (i < 49152)  v = Wb0[i - 32768];
      else if (i < 65536)  v = Wb1[i - 49152];
      else if (i < 114688) v = Wm[i - 65536];
      else {
        int o = i - 114688;           // [0, 16384)
        int half = o >> 13;           // 0 -> Wo0, 1 -> Wo1
        int idx = o & 8191;
        int r = idx >> 7, c = idx & 127;
        v = Wo[r * 256 + half * 128 + c];
      }
      Wout[i] = f2bf(v);
    }
    return;
  }
  int i = blockIdx.x * blockDim.x + threadIdx.x;
  if (i > n) return;
  const int* row = blockIdx.y ? rowB : rowA;
  int* rp = blockIdx.y ? rpb : rpa;
  int lo = 0, hi = E;
  while (lo < hi) {
    int mid = (lo + hi) >> 1;
    if (row[mid] < i) lo = mid + 1; else hi = mid;
  }
  rp[i] = lo;
}

// ---------------------------------------------------------------------------
// SpMM row body (v5, proven): Y[g,:] = sum_e val[e] * X[col[e],:]
// WIDTH bf16 features; WIDTH/8 lanes per row, 16 B gather per lane.
// Depth-2 software pipeline: col/val prefetched 2 batches ahead.
// ---------------------------------------------------------------------------
template <int WIDTH, bool OUTF32>
__device__ __forceinline__ void spmm_rows(
    const int* __restrict__ rowptr, const int* __restrict__ col,
    const float* __restrict__ val, const unsigned short* __restrict__ X,
    void* __restrict__ Yv, int n, int bx)
{
  constexpr int LPR = WIDTH / 8;        // lanes per row
  constexpr int GPB = 256 / LPR;        // row-groups per block
  int g = bx * GPB + ((int)threadIdx.x / LPR);
  int lane = threadIdx.x & (LPR - 1);
  if (g >= n) return;
  int e0 = rowptr[g], e1 = rowptr[g + 1];

  float a0 = 0.f, a1 = 0.f, a2 = 0.f, a3 = 0.f;
  float a4 = 0.f, a5 = 0.f, a6 = 0.f, a7 = 0.f;
  const size_t loff = (size_t)lane * 8;

  auto gat = [&](int c) -> uint4 {
    return *(const uint4*)(X + (size_t)c * WIDTH + loff);
  };
  auto fma1 = [&](float v, uint4 w) {
    a0 = fmaf(v, bf_lo(w.x), a0); a1 = fmaf(v, bf_hi(w.x), a1);
    a2 = fmaf(v, bf_lo(w.y), a2); a3 = fmaf(v, bf_hi(w.y), a3);
    a4 = fmaf(v, bf_lo(w.z), a4); a5 = fmaf(v, bf_hi(w.z), a5);
    a6 = fmaf(v, bf_lo(w.w), a6); a7 = fmaf(v, bf_hi(w.w), a7);
  };
  auto accum = [&](int c, float v) { fma1(v, gat(c)); };

  int e = e0;
  int epro = (e0 + 3) & ~3;             // align to 4 for vector col/val loads
  if (epro > e1) epro = e1;
  for (; e < epro; ++e) accum(col[e], val[e]);

  int nb = (e1 - e) >> 2;               // full 4-edge batches
  if (nb > 0) {
    int4   cA = *(const int4*)(col + e);
    float4 vA = *(const float4*)(val + e);
    int4   cB = cA; float4 vB = vA;
    if (nb > 1) { cB = *(const int4*)(col + e + 4); vB = *(const float4*)(val + e + 4); }
    uint4 w0 = gat(cA.x), w1 = gat(cA.y), w2 = gat(cA.z), w3 = gat(cA.w);
    for (int t = 0; t < nb - 1; ++t) {
      int4 cC = cB; float4 vC = vB;
      if (t + 2 < nb) {
        cC = *(const int4*)(col + e + 4 * (t + 2));
        vC = *(const float4*)(val + e + 4 * (t + 2));
      }
      uint4 u0 = gat(cB.x), u1 = gat(cB.y), u2 = gat(cB.z), u3 = gat(cB.w);
      fma1(vA.x, w0); fma1(vA.y, w1); fma1(vA.z, w2); fma1(vA.w, w3);
      vA = vB; vB = vC; cB = cC;
      w0 = u0; w1 = u1; w2 = u2; w3 = u3;
    }
    fma1(vA.x, w0); fma1(vA.y, w1); fma1(vA.z, w2); fma1(vA.w, w3);
    e += nb * 4;
  }
  for (; e < e1; ++e) accum(col[e], val[e]);

  if (OUTF32) {
    float* Y = (float*)Yv;
    float4 o0; o0.x = a0; o0.y = a1; o0.z = a2; o0.w = a3;
    float4 o1; o1.x = a4; o1.y = a5; o1.z = a6; o1.w = a7;
    *(float4*)(Y + (size_t)g * WIDTH + lane * 8) = o0;
    *(float4*)(Y + (size_t)g * WIDTH + lane * 8 + 4) = o1;
  } else {
    uint4 o;
    o.x = pack2(a0, a1); o.y = pack2(a2, a3);
    o.z = pack2(a4, a5); o.w = pack2(a6, a7);
    *(uint4*)((unsigned short*)Yv + (size_t)g * WIDTH + loff) = o;
  }
}

// ---------------------------------------------------------------------------
// GEMM building blocks (bodies take bx so they can be embedded in merged
// launches). Block: 256 thr = 4 waves 2x2; tile 128 rows x HOUT cols.
// X tile staged in LDS (padded); W fragments read from global (L1/L2-hot).
// ---------------------------------------------------------------------------
#define LDXP 136   // padded LDS row stride (bf16 units)

__device__ inline void stage_bf16(const unsigned short* __restrict__ Xp,
                                  unsigned short* Xs, int row0, int n,
                                  int rloc, int c8)
{
#pragma unroll
  for (int p = 0; p < 8; ++p) {
    int r = p * 16 + rloc;
    int gr = row0 + r;
    uint4 v = make_uint4(0u, 0u, 0u, 0u);
    if (gr < n) v = *(const uint4*)(Xp + (size_t)gr * 128 + c8);
    *(uint4*)(Xs + r * LDXP + c8) = v;
  }
}

template <int NT>
__device__ inline void mfma_phase(const unsigned short* __restrict__ W, int wld,
                                  int kc, const unsigned short* Xs,
                                  int wm, int wn, int l15, int quad,
                                  floatx4 (&acc)[4][NT])
{
#pragma unroll
  for (int k0 = 0; k0 < 128; k0 += 32) {
    const int ko = k0 + quad * 8;
    short8 aW[NT], bX[4];
#pragma unroll
    for (int j = 0; j < NT; ++j)
      aW[j] = *(const short8*)(W + (size_t)(wn * (16 * NT) + j * 16 + l15) * wld + kc + ko);
#pragma unroll
    for (int i = 0; i < 4; ++i)
      bX[i] = *(const short8*)(Xs + (wm * 64 + i * 16 + l15) * LDXP + ko);
#pragma unroll
    for (int i = 0; i < 4; ++i)
#pragma unroll
      for (int j = 0; j < NT; ++j)
        acc[i][j] = __builtin_amdgcn_mfma_f32_16x16x32_bf16(aW[j], bX[i], acc[i][j], 0, 0, 0);
  }
}

// Y = (relu?)(X @ W.T [+ b] [+ add]); X = up to 3 bf16 slabs (free concat);
// W pointer may be pre-offset into a wider matrix (wld = leading stride).
template <int K, int HOUT, bool RELU, bool OUTBF, bool ADDEND, bool BIAS>
__device__ __forceinline__ void gemm_body(
    unsigned short* Xs,
    const unsigned short* __restrict__ X0, const unsigned short* __restrict__ X1,
    const unsigned short* __restrict__ X2, const unsigned short* __restrict__ W,
    int wld, const float* __restrict__ b, const float* __restrict__ add,
    void* __restrict__ Yv, int n, int bx)
{
  constexpr int NT = HOUT / 32;
  const int tid = threadIdx.x;
  const int lane = tid & 63;
  const int wave = tid >> 6;
  const int wm = wave >> 1;
  const int wn = wave & 1;
  const int l15 = lane & 15;
  const int quad = lane >> 4;
  const int row0 = bx * 128;
  const int c8 = (tid & 15) * 8;
  const int rloc = tid >> 4;

  floatx4 acc[4][NT];
#pragma unroll
  for (int i = 0; i < 4; ++i)
#pragma unroll
    for (int j = 0; j < NT; ++j) acc[i][j] = (floatx4){0.f, 0.f, 0.f, 0.f};

  for (int kc = 0; kc < K; kc += 128) {
    const unsigned short* Xp = (kc == 0) ? X0 : (kc == 128) ? X1 : X2;
    if (kc) __syncthreads();
    stage_bf16(Xp, Xs, row0, n, rloc, c8);
    __syncthreads();
    mfma_phase<NT>(W, wld, kc, Xs, wm, wn, l15, quad, acc);
  }

#pragma unroll
  for (int i = 0; i < 4; ++i) {
    int r = row0 + wm * 64 + i * 16 + l15;
    if (r >= n) continue;
#pragma unroll
    for (int j = 0; j < NT; ++j) {
      int c0 = wn * (16 * NT) + j * 16 + quad * 4;
      float4 bb = make_float4(0.f, 0.f, 0.f, 0.f);
      if (BIAS) bb = *(const float4*)(b + c0);
      float v0 = acc[i][j][0] + bb.x;
      float v1 = acc[i][j][1] + bb.y;
      float v2 = acc[i][j][2] + bb.z;
      float v3 = acc[i][j][3] + bb.w;
      if (ADDEND) {
        float4 ad = *(const float4*)(add + (size_t)r * HOUT + c0);
        v0 += ad.x; v1 += ad.y; v2 += ad.z; v3 += ad.w;
      }
      if (RELU) {
        v0 = fmaxf(v0, 0.f); v1 = fmaxf(v1, 0.f);
        v2 = fmaxf(v2, 0.f); v3 = fmaxf(v3, 0.f);
      }
      if (OUTBF) {
        uint2 o; o.x = pack2(v0, v1); o.y = pack2(v2, v3);
        *(uint2*)((unsigned short*)Yv + (size_t)r * HOUT + c0) = o;
      } else {
        float4 o; o.x = v0; o.y = v1; o.z = v2; o.w = v3;
        *(float4*)((float*)Yv + (size_t)r * HOUT + c0) = o;
      }
    }
  }
}

// Q = (relu(B@Wa1.T + ba1)) @ Wo0.T — two chained MFMA stages through LDS.
__device__ __forceinline__ void chain_body(
    unsigned short* Xs, const unsigned short* __restrict__ X,
    const unsigned short* __restrict__ W1, const float* __restrict__ b1,
    const unsigned short* __restrict__ W2, unsigned short* __restrict__ Q,
    int n, int bx)
{
  const int tid = threadIdx.x;
  const int lane = tid & 63;
  const int wave = tid >> 6;
  const int wm = wave >> 1;
  const int wn = wave & 1;
  const int l15 = lane & 15;
  const int quad = lane >> 4;
  const int row0 = bx * 128;
  const int c8 = (tid & 15) * 8;
  const int rloc = tid >> 4;

  stage_bf16(X, Xs, row0, n, rloc, c8);
  __syncthreads();

  floatx4 acc1[4][4];
#pragma unroll
  for (int i = 0; i < 4; ++i)
#pragma unroll
    for (int j = 0; j < 4; ++j) acc1[i][j] = (floatx4){0.f, 0.f, 0.f, 0.f};
  mfma_phase<4>(W1, 128, 0, Xs, wm, wn, l15, quad, acc1);
  __syncthreads();   // all stage-1 reads of Xs done before overwrite

#pragma unroll
  for (int i = 0; i < 4; ++i) {
    int r2 = wm * 64 + i * 16 + l15;
#pragma unroll
    for (int j = 0; j < 4; ++j) {
      int c2 = wn * 64 + j * 16 + quad * 4;
      float4 bb = *(const float4*)(b1 + c2);
      float v0 = fmaxf(acc1[i][j][0] + bb.x, 0.f);
      float v1 = fmaxf(acc1[i][j][1] + bb.y, 0.f);
      float v2 = fmaxf(acc1[i][j][2] + bb.z, 0.f);
      float v3 = fmaxf(acc1[i][j][3] + bb.w, 0.f);
      uint2 o; o.x = pack2(v0, v1); o.y = pack2(v2, v3);
      *(uint2*)(Xs + r2 * LDXP + c2) = o;
    }
  }
  __syncthreads();

  floatx4 acc2[4][2];
#pragma unroll
  for (int i = 0; i < 4; ++i)
#pragma unroll
    for (int j = 0; j < 2; ++j) acc2[i][j] = (floatx4){0.f, 0.f, 0.f, 0.f};
  mfma_phase<2>(W2, 128, 0, Xs, wm, wn, l15, quad, acc2);

#pragma unroll
  for (int i = 0; i < 4; ++i) {
    int r = row0 + wm * 64 + i * 16 + l15;
    if (r >= n) continue;
#pragma unroll
    for (int j = 0; j < 2; ++j) {
      int c0 = wn * 32 + j * 16 + quad * 4;
      uint2 o;
      o.x = pack2(acc2[i][j][0], acc2[i][j][1]);
      o.y = pack2(acc2[i][j][2], acc2[i][j][3]);
      *(uint2*)(Q + (size_t)r * 64 + c0) = o;
    }
  }
}

// ---------------------------------------------------------------------------
// Kernels
// ---------------------------------------------------------------------------

// standalone GEMM wrapper
template <int K, int HOUT, bool RELU, bool OUTBF, bool ADDEND, bool BIAS>
__global__ __launch_bounds__(256, 2) void gemm_std_kernel(
    const unsigned short* __restrict__ X0, const unsigned short* __restrict__ X1,
    const unsigned short* __restrict__ X2, const unsigned short* __restrict__ W,
    int wld, const float* __restrict__ b, const float* __restrict__ add,
    void* __restrict__ Yv, int n)
{
  __shared__ unsigned short Xs[128 * LDXP];
  gemm_body<K, HOUT, RELU, OUTBF, ADDEND, BIAS>(Xs, X0, X1, X2, W, wld, b, add,
                                                Yv, n, blockIdx.x);
}

// A = relu(x@W1.T+b1), C = relu(x@W2.T+b2) from fp32 x, shared X staging.
__global__ __launch_bounds__(256, 2) void gemm_dual_f32_kernel(
    const float* __restrict__ X, const unsigned short* __restrict__ W1,
    const unsigned short* __restrict__ W2, const float* __restrict__ b1,
    const float* __restrict__ b2, unsigned short* __restrict__ Y1,
    unsigned short* __restrict__ Y2, int n)
{
  constexpr int NT = 4;  // HOUT = 128
  __shared__ unsigned short Xs[128 * LDXP];
  const int tid = threadIdx.x;
  const int lane = tid & 63;
  const int wave = tid >> 6;
  const int wm = wave >> 1;
  const int wn = wave & 1;
  const int l15 = lane & 15;
  const int quad = lane >> 4;
  const int row0 = blockIdx.x * 128;
  const int c8 = (tid & 15) * 8;
  const int rloc = tid >> 4;

#pragma unroll
  for (int p = 0; p < 8; ++p) {
    int r = p * 16 + rloc;
    int gr = row0 + r;
    uint4 o = make_uint4(0u, 0u, 0u, 0u);
    if (gr < n) {
      float4 f0 = *(const float4*)(X + (size_t)gr * 128 + c8);
      float4 f1 = *(const float4*)(X + (size_t)gr * 128 + c8 + 4);
      o.x = pack2(f0.x, f0.y); o.y = pack2(f0.z, f0.w);
      o.z = pack2(f1.x, f1.y); o.w = pack2(f1.z, f1.w);
    }
    *(uint4*)(Xs + r * LDXP + c8) = o;
  }
  __syncthreads();

  for (int s = 0; s < 2; ++s) {
    const unsigned short* W = s ? W2 : W1;
    const float* b = s ? b2 : b1;
    unsigned short* Y = s ? Y2 : Y1;
    floatx4 acc[4][NT];
#pragma unroll
    for (int i = 0; i < 4; ++i)
#pragma unroll
      for (int j = 0; j < NT; ++j) acc[i][j] = (floatx4){0.f, 0.f, 0.f, 0.f};
    mfma_phase<NT>(W, 128, 0, Xs, wm, wn, l15, quad, acc);
#pragma unroll
    for (int i = 0; i < 4; ++i) {
      int r = row0 + wm * 64 + i * 16 + l15;
      if (r >= n) continue;
#pragma unroll
      for (int j = 0; j < NT; ++j) {
        int c0 = wn * 64 + j * 16 + quad * 4;
        float4 bb = *(const float4*)(b + c0);
        float v0 = fmaxf(acc[i][j][0] + bb.x, 0.f);
        float v1 = fmaxf(acc[i][j][1] + bb.y, 0.f);
        float v2 = fmaxf(acc[i][j][2] + bb.z, 0.f);
        float v3 = fmaxf(acc[i][j][3] + bb.w, 0.f);
        uint2 o; o.x = pack2(v0, v1); o.y = pack2(v2, v3);
        *(uint2*)(Y + (size_t)r * 128 + c0) = o;
      }
    }
  }
}

// y=0: spmm_a A->B; y=1: spmm_b C->B2; y=2: P1 = C·Wm0^T + bm (fp32)
__global__ __launch_bounds__(256, 3) void spmm1_p1_kernel(
    const int* __restrict__ rpa, const int* __restrict__ cola,
    const float* __restrict__ vala, const unsigned short* __restrict__ A,
    unsigned short* __restrict__ B,
    const int* __restrict__ rpb, const int* __restrict__ colb,
    const float* __restrict__ valb, const unsigned short* __restrict__ C,
    unsigned short* __restrict__ B2,
    const unsigned short* __restrict__ Wm0, const float* __restrict__ bm,
    float* __restrict__ P1, int n)
{
  __shared__ unsigned short Xs[128 * LDXP];
  if (blockIdx.y == 0) {
    spmm_rows<128, false>(rpa, cola, vala, A, B, n, blockIdx.x);
  } else if (blockIdx.y == 1) {
    spmm_rows<128, false>(rpb, colb, valb, C, B2, n, blockIdx.x);
  } else {
    if ((int)blockIdx.x >= (n + 127) >> 7) return;
    gemm_body<128, 128, false, false, false, true>(
        Xs, C, nullptr, nullptr, Wm0, 384, bm, nullptr, P1, n, blockIdx.x);
  }
}

// y=0: chain Q = relu(B·Wa1^T+ba1)·Wo0^T; y=1: D = relu(B2·Wb1^T+bb1)
__global__ __launch_bounds__(256, 2) void chain_g1_kernel(
    const unsigned short* __restrict__ B, const unsigned short* __restrict__ Wa1,
    const float* __restrict__ ba1, const unsigned short* __restrict__ Wo0,
    unsigned short* __restrict__ Q,
    const unsigned short* __restrict__ B2, const unsigned short* __restrict__ Wb1,
    const float* __restrict__ bb1, unsigned short* __restrict__ D, int n)
{
  __shared__ unsigned short Xs[128 * LDXP];
  if (blockIdx.y == 0)
    chain_body(Xs, B, Wa1, ba1, Wo0, Q, n, blockIdx.x);
  else
    gemm_body<128, 128, true, true, false, true>(
        Xs, B2, nullptr, nullptr, Wb1, 128, bb1, nullptr, D, n, blockIdx.x);
}

// y=0: spmm_b D->B (g2); y=1: spmm_a Q->Pout (64-wide, f32);
// y=2: P2 = P1 + D·Wm1^T (fp32)
__global__ __launch_bounds__(256, 3) void spmm2_p2_kernel(
    const int* __restrict__ rpb, const int* __restrict__ colb,
    const float* __restrict__ valb, const unsigned short* __restrict__ D,
    unsigned short* __restrict__ B,
    const int* __restrict__ rpa, const int* __restrict__ cola,
    const float* __restrict__ vala, const unsigned short* __restrict__ Q,
    float* __restrict__ Pout,
    const unsigned short* __restrict__ Wm1, const float* __restrict__ P1,
    float* __restrict__ P2, int n)
{
  __shared__ unsigned short Xs[128 * LDXP];
  if (blockIdx.y == 0) {
    spmm_rows<128, false>(rpb, colb, valb, D, B, n, blockIdx.x);
  } else if (blockIdx.y == 1) {
    spmm_rows<64, true>(rpa, cola, vala, Q, Pout, n, blockIdx.x);
  } else {
    if ((int)blockIdx.x >= (n + 127) >> 7) return;
    gemm_body<128, 128, false, false, true, false>(
        Xs, D, nullptr, nullptr, Wm1, 384, nullptr, P1, P2, n, blockIdx.x);
  }
}

extern "C" void kernel_launch(void* const* d_in, const int* in_sizes, int n_in,
                              void* d_out, int out_size, void* d_ws, size_t ws_size,
                              hipStream_t stream)
{
  const float* x     = (const float*)d_in[0];
  const int*   row_a = (const int*)d_in[1];
  const int*   col_a = (const int*)d_in[2];
  const float* val_a = (const float*)d_in[3];
  const int*   row_b = (const int*)d_in[4];
  const int*   col_b = (const int*)d_in[5];
  const float* val_b = (const float*)d_in[6];
  const float* Wa0 = (const float*)d_in[7];  const float* ba0 = (const float*)d_in[8];
  const float* Wa1 = (const float*)d_in[9];  const float* ba1 = (const float*)d_in[10];
  const float* Wb0 = (const float*)d_in[11]; const float* bb0 = (const float*)d_in[12];
  const float* Wb1 = (const float*)d_in[13]; const float* bb1 = (const float*)d_in[14];
  const float* Wm  = (const float*)d_in[15]; const float* bm  = (const float*)d_in[16];
  const float* Wo  = (const float*)d_in[17]; const float* bo  = (const float*)d_in[18];
  float* out = (float*)d_out;

  const int n = in_sizes[0] / 128;   // 50000
  const int E = in_sizes[1];         // 800000

  char* ws = (char*)d_ws;
  size_t off = 0;
  auto alloc = [&](size_t bytes) {
    void* p = ws + off;
    off = (off + bytes + 255) & ~(size_t)255;
    return p;
  };
  int* rpa = (int*)alloc((size_t)(n + 1) * sizeof(int));
  int* rpb = (int*)alloc((size_t)(n + 1) * sizeof(int));
  unsigned short* Wcat = (unsigned short*)alloc(131072 * sizeof(unsigned short));
  const size_t slab = (size_t)n * 128 * sizeof(unsigned short);
  unsigned short* A  = (unsigned short*)alloc(slab);   // branch-a hidden
  unsigned short* C  = (unsigned short*)alloc(slab);   // g0
  unsigned short* B  = (unsigned short*)alloc(slab);   // graph-a sp1 out / g2
  unsigned short* B2 = (unsigned short*)alloc(slab);   // graph-b sp1 out
  unsigned short* D  = (unsigned short*)alloc(slab);   // g1
  unsigned short* A3 = (unsigned short*)alloc(slab);   // x_b
  unsigned short* Q  = (unsigned short*)alloc((size_t)n * 64 * sizeof(unsigned short));
  float* Pout = (float*)alloc((size_t)n * 64 * sizeof(float));  // x_a @ Wo0^T
  float* P1   = (float*)alloc((size_t)n * 128 * sizeof(float)); // g0 Wm0^T + bm
  float* P2   = (float*)alloc((size_t)n * 128 * sizeof(float)); // P1 + g1 Wm1^T

  const unsigned short* Wa0b = Wcat;
  const unsigned short* Wa1b = Wcat + 16384;
  const unsigned short* Wb0b = Wcat + 32768;
  const unsigned short* Wb1b = Wcat + 49152;
  const unsigned short* Wmb  = Wcat + 65536;   // [128, 384]
  const unsigned short* Wo0b = Wcat + 114688;
  const unsigned short* Wo1b = Wcat + 122880;

  dim3 blk(256);
  dim3 g_setup((n + 1 + 255) / 256, 3);
  dim3 g_lin((n + 127) / 128);
  dim3 g_sp3((n + 15) / 16, 3);

  setup_kernel<<<g_setup, blk, 0, stream>>>(row_a, row_b, E, n, rpa, rpb,
                                            Wa0, Wa1, Wb0, Wb1, Wm, Wo, Wcat);

  // A = relu(x Wa0^T + ba0), C = relu(x Wb0^T + bb0)   (shared x staging)
  gemm_dual_f32_kernel<<<g_lin, blk, 0, stream>>>(x, Wa0b, Wb0b, ba0, bb0, A, C, n);

  // spmm_a(A->B) || spmm_b(C->B2) || P1 = g0 Wm0^T + bm
  spmm1_p1_kernel<<<g_sp3, blk, 0, stream>>>(
      rpa, col_a, val_a, A, B,
      rpb, col_b, val_b, C, B2,
      Wmb, bm, P1, n);

  // chain: Q = relu(B Wa1^T + ba1) Wo0^T  ||  g1: D = relu(B2 Wb1^T + bb1)
  dim3 g_cg((n + 127) / 128, 2);
  chain_g1_kernel<<<g_cg, blk, 0, stream>>>(
      B, Wa1b, ba1, Wo0b, Q,
      B2, Wb1b, bb1, D, n);

  // spmm_b(D->B, g2) || spmm_a(Q->Pout) || P2 = P1 + g1 Wm1^T
  spmm2_p2_kernel<<<g_sp3, blk, 0, stream>>>(
      rpb, col_b, val_b, D, B,
      rpa, col_a, val_a, Q, Pout,
      Wmb + 128, P1, P2, n);

  // A3 = relu(P2 + g2 Wm2^T)
  gemm_std_kernel<128, 128, true, true, true, false><<<g_lin, blk, 0, stream>>>(
      B, nullptr, nullptr, Wmb + 256, 384, nullptr, P2, A3, n);

  // out = A3 Wo1^T + bo + Pout   (fp32 out)
  gemm_std_kernel<128, 64, false, false, true, true><<<g_lin, blk, 0, stream>>>(
      A3, nullptr, nullptr, Wo1b, 128, bo, Pout, out, n);
}

// Round 6
// 329.686 us; speedup vs baseline: 1.2340x; 1.0250x over previous
//
#include <hip/hip_runtime.h>

// ---------------------------------------------------------------------------
// DualGCN v8: SpMM->GEMM fusion at 128-row tile granularity (4 launches).
//   fused1 y=0: Q  = (relu(spmm_a(A)·Wa1^T+ba1))·Wo0^T   [B slab eliminated]
//   fused1 y=1: D  = relu(spmm_b(C)·Wb1^T+bb1)           [B2 slab eliminated]
//   fused2:     out = relu(g0·Wm0+g1·Wm1+spmm_b(D)·Wm2+bm)·Wo1^T + bo
//                     + spmm_a(Q)->out (f32, written directly)
//               [g2, A3, Pout slabs eliminated]
//   SpMM tile results live in the same 34.8 KB LDS the GEMM stages through
//   -> no occupancy penalty (4 blocks/CU), unlike v7's merge.
// N=50000, E=800000, H=128, OUT=64.
// ---------------------------------------------------------------------------

typedef short short8 __attribute__((ext_vector_type(8)));
typedef float floatx4 __attribute__((ext_vector_type(4)));

#define LDXP 136   // padded LDS row stride (bf16 units)

__device__ inline unsigned short f2bf(float f) {
  unsigned u = __builtin_bit_cast(unsigned, f);
  u += 0x7fffu + ((u >> 16) & 1u);      // round-to-nearest-even
  return (unsigned short)(u >> 16);
}
__device__ inline unsigned pack2(float a, float b) {
  return (unsigned)f2bf(a) | ((unsigned)f2bf(b) << 16);
}
__device__ inline float bf_lo(unsigned w) {
  return __builtin_bit_cast(float, w << 16);
}
__device__ inline float bf_hi(unsigned w) {
  return __builtin_bit_cast(float, w & 0xffff0000u);
}

// y=0: rowptr for graph a; y=1: rowptr for graph b; y=2: convert weights.
// Wo de-interleaved into Wo0 = Wo[:, :128] and Wo1 = Wo[:, 128:].
__global__ __launch_bounds__(256) void setup_kernel(
    const int* __restrict__ rowA, const int* __restrict__ rowB,
    int E, int n, int* __restrict__ rpa, int* __restrict__ rpb,
    const float* __restrict__ Wa0, const float* __restrict__ Wa1,
    const float* __restrict__ Wb0, const float* __restrict__ Wb1,
    const float* __restrict__ Wm,  const float* __restrict__ Wo,
    unsigned short* __restrict__ Wout)
{
  if (blockIdx.y == 2) {
    for (int i = blockIdx.x * 256 + threadIdx.x; i < 131072; i += gridDim.x * 256) {
      float v;
      if      (i < 16384)  v = Wa0[i];
      else if (i < 32768)  v = Wa1[i - 16384];
      else if (i < 49152)  v = Wb0[i - 32768];
      else if (i < 65536)  v = Wb1[i - 49152];
      else if (i < 114688) v = Wm[i - 65536];
      else {
        int o = i - 114688;           // [0, 16384)
        int half = o >> 13;           // 0 -> Wo0, 1 -> Wo1
        int idx = o & 8191;
        int r = idx >> 7, c = idx & 127;
        v = Wo[r * 256 + half * 128 + c];
      }
      Wout[i] = f2bf(v);
    }
    return;
  }
  int i = blockIdx.x * blockDim.x + threadIdx.x;
  if (i > n) return;
  const int* row = blockIdx.y ? rowB : rowA;
  int* rp = blockIdx.y ? rpb : rpa;
  int lo = 0, hi = E;
  while (lo < hi) {
    int mid = (lo + hi) >> 1;
    if (row[mid] < i) lo = mid + 1; else hi = mid;
  }
  rp[i] = lo;
}

// ---------------------------------------------------------------------------
// SpMM row core (v5 streaming, proven): a[0..7] = sum_e val[e]*X[col[e], 8*lane..]
// Depth-2 software pipeline: col/val prefetched 2 batches ahead.
// ---------------------------------------------------------------------------
template <int WIDTH>
__device__ __forceinline__ void spmm_row_core(
    int e0, int e1, const int* __restrict__ col, const float* __restrict__ val,
    const unsigned short* __restrict__ X, size_t loff, float a[8])
{
  auto gat = [&](int c) -> uint4 {
    return *(const uint4*)(X + (size_t)c * WIDTH + loff);
  };
  auto fma1 = [&](float v, uint4 w) {
    a[0] = fmaf(v, bf_lo(w.x), a[0]); a[1] = fmaf(v, bf_hi(w.x), a[1]);
    a[2] = fmaf(v, bf_lo(w.y), a[2]); a[3] = fmaf(v, bf_hi(w.y), a[3]);
    a[4] = fmaf(v, bf_lo(w.z), a[4]); a[5] = fmaf(v, bf_hi(w.z), a[5]);
    a[6] = fmaf(v, bf_lo(w.w), a[6]); a[7] = fmaf(v, bf_hi(w.w), a[7]);
  };

  int e = e0;
  int epro = (e0 + 3) & ~3;             // align to 4 for vector col/val loads
  if (epro > e1) epro = e1;
  for (; e < epro; ++e) fma1(val[e], gat(col[e]));

  int nb = (e1 - e) >> 2;               // full 4-edge batches
  if (nb > 0) {
    int4   cA = *(const int4*)(col + e);
    float4 vA = *(const float4*)(val + e);
    int4   cB = cA; float4 vB = vA;
    if (nb > 1) { cB = *(const int4*)(col + e + 4); vB = *(const float4*)(val + e + 4); }
    uint4 w0 = gat(cA.x), w1 = gat(cA.y), w2 = gat(cA.z), w3 = gat(cA.w);
    for (int t = 0; t < nb - 1; ++t) {
      int4 cC = cB; float4 vC = vB;
      if (t + 2 < nb) {
        cC = *(const int4*)(col + e + 4 * (t + 2));
        vC = *(const float4*)(val + e + 4 * (t + 2));
      }
      uint4 u0 = gat(cB.x), u1 = gat(cB.y), u2 = gat(cB.z), u3 = gat(cB.w);
      fma1(vA.x, w0); fma1(vA.y, w1); fma1(vA.z, w2); fma1(vA.w, w3);
      vA = vB; vB = vC; cB = cC;
      w0 = u0; w1 = u1; w2 = u2; w3 = u3;
    }
    fma1(vA.x, w0); fma1(vA.y, w1); fma1(vA.z, w2); fma1(vA.w, w3);
    e += nb * 4;
  }
  for (; e < e1; ++e) fma1(val[e], gat(col[e]));
}

// 128-wide SpMM for rows [row0, row0+128) -> LDS tile (bf16, LDXP stride).
// Rows >= n are zero-filled (their GEMM outputs are discarded).
__device__ __forceinline__ void spmm_tile_to_lds(
    const int* __restrict__ rowptr, const int* __restrict__ col,
    const float* __restrict__ val, const unsigned short* __restrict__ X,
    unsigned short* Xs, int n, int row0)
{
  const int grp  = (int)threadIdx.x >> 4;   // 16 groups of 16 lanes
  const int lane = threadIdx.x & 15;
  const size_t loff = (size_t)lane * 8;
#pragma unroll
  for (int p = 0; p < 8; ++p) {
    int rl = p * 16 + grp;
    int r = row0 + rl;
    float a[8] = {0.f, 0.f, 0.f, 0.f, 0.f, 0.f, 0.f, 0.f};
    if (r < n) {
      int e0 = rowptr[r], e1 = rowptr[r + 1];
      spmm_row_core<128>(e0, e1, col, val, X, loff, a);
    }
    uint4 o;
    o.x = pack2(a[0], a[1]); o.y = pack2(a[2], a[3]);
    o.z = pack2(a[4], a[5]); o.w = pack2(a[6], a[7]);
    *(uint4*)(Xs + rl * LDXP + lane * 8) = o;
  }
}

// 64-wide SpMM for rows [row0, row0+128) -> f32 global (out base, stride 64).
__device__ __forceinline__ void spmm_tile64_to_out(
    const int* __restrict__ rowptr, const int* __restrict__ col,
    const float* __restrict__ val, const unsigned short* __restrict__ X,
    float* __restrict__ out, int n, int row0)
{
  const int grp  = (int)threadIdx.x >> 3;   // 32 groups of 8 lanes
  const int lane = threadIdx.x & 7;
  const size_t loff = (size_t)lane * 8;
#pragma unroll
  for (int p = 0; p < 4; ++p) {
    int r = row0 + p * 32 + grp;
    if (r >= n) continue;
    float a[8] = {0.f, 0.f, 0.f, 0.f, 0.f, 0.f, 0.f, 0.f};
    int e0 = rowptr[r], e1 = rowptr[r + 1];
    spmm_row_core<64>(e0, e1, col, val, X, loff, a);
    float4 o0; o0.x = a[0]; o0.y = a[1]; o0.z = a[2]; o0.w = a[3];
    float4 o1; o1.x = a[4]; o1.y = a[5]; o1.z = a[6]; o1.w = a[7];
    *(float4*)(out + (size_t)r * 64 + lane * 8) = o0;
    *(float4*)(out + (size_t)r * 64 + lane * 8 + 4) = o1;
  }
}

// ---------------------------------------------------------------------------
// GEMM building blocks. Block: 256 thr = 4 waves 2x2; tile 128 rows x HOUT.
// X operand in LDS; W fragments read from global (L1/L2-hot).
// ---------------------------------------------------------------------------
__device__ inline void stage_bf16(const unsigned short* __restrict__ Xp,
                                  unsigned short* Xs, int row0, int n,
                                  int rloc, int c8)
{
#pragma unroll
  for (int p = 0; p < 8; ++p) {
    int r = p * 16 + rloc;
    int gr = row0 + r;
    uint4 v = make_uint4(0u, 0u, 0u, 0u);
    if (gr < n) v = *(const uint4*)(Xp + (size_t)gr * 128 + c8);
    *(uint4*)(Xs + r * LDXP + c8) = v;
  }
}

template <int NT>
__device__ inline void mfma_phase(const unsigned short* __restrict__ W, int wld,
                                  const unsigned short* Xs,
                                  int wm, int wn, int l15, int quad,
                                  floatx4 (&acc)[4][NT])
{
#pragma unroll
  for (int k0 = 0; k0 < 128; k0 += 32) {
    const int ko = k0 + quad * 8;
    short8 aW[NT], bX[4];
#pragma unroll
    for (int j = 0; j < NT; ++j)
      aW[j] = *(const short8*)(W + (size_t)(wn * (16 * NT) + j * 16 + l15) * wld + ko);
#pragma unroll
    for (int i = 0; i < 4; ++i)
      bX[i] = *(const short8*)(Xs + (wm * 64 + i * 16 + l15) * LDXP + ko);
#pragma unroll
    for (int i = 0; i < 4; ++i)
#pragma unroll
      for (int j = 0; j < NT; ++j)
        acc[i][j] = __builtin_amdgcn_mfma_f32_16x16x32_bf16(aW[j], bX[i], acc[i][j], 0, 0, 0);
  }
}

// ---------------------------------------------------------------------------
// Kernels
// ---------------------------------------------------------------------------

// A = relu(x@W1.T+b1), C = relu(x@W2.T+b2) from fp32 x, shared X staging.
__global__ __launch_bounds__(256, 2) void gemm_dual_f32_kernel(
    const float* __restrict__ X, const unsigned short* __restrict__ W1,
    const unsigned short* __restrict__ W2, const float* __restrict__ b1,
    const float* __restrict__ b2, unsigned short* __restrict__ Y1,
    unsigned short* __restrict__ Y2, int n)
{
  constexpr int NT = 4;  // HOUT = 128
  __shared__ unsigned short Xs[128 * LDXP];
  const int tid = threadIdx.x;
  const int lane = tid & 63;
  const int wave = tid >> 6;
  const int wm = wave >> 1;
  const int wn = wave & 1;
  const int l15 = lane & 15;
  const int quad = lane >> 4;
  const int row0 = blockIdx.x * 128;
  const int c8 = (tid & 15) * 8;
  const int rloc = tid >> 4;

#pragma unroll
  for (int p = 0; p < 8; ++p) {
    int r = p * 16 + rloc;
    int gr = row0 + r;
    uint4 o = make_uint4(0u, 0u, 0u, 0u);
    if (gr < n) {
      float4 f0 = *(const float4*)(X + (size_t)gr * 128 + c8);
      float4 f1 = *(const float4*)(X + (size_t)gr * 128 + c8 + 4);
      o.x = pack2(f0.x, f0.y); o.y = pack2(f0.z, f0.w);
      o.z = pack2(f1.x, f1.y); o.w = pack2(f1.z, f1.w);
    }
    *(uint4*)(Xs + r * LDXP + c8) = o;
  }
  __syncthreads();

  for (int s = 0; s < 2; ++s) {
    const unsigned short* W = s ? W2 : W1;
    const float* b = s ? b2 : b1;
    unsigned short* Y = s ? Y2 : Y1;
    floatx4 acc[4][NT];
#pragma unroll
    for (int i = 0; i < 4; ++i)
#pragma unroll
      for (int j = 0; j < NT; ++j) acc[i][j] = (floatx4){0.f, 0.f, 0.f, 0.f};
    mfma_phase<NT>(W, 128, Xs, wm, wn, l15, quad, acc);
#pragma unroll
    for (int i = 0; i < 4; ++i) {
      int r = row0 + wm * 64 + i * 16 + l15;
      if (r >= n) continue;
#pragma unroll
      for (int j = 0; j < NT; ++j) {
        int c0 = wn * 64 + j * 16 + quad * 4;
        float4 bb = *(const float4*)(b + c0);
        float v0 = fmaxf(acc[i][j][0] + bb.x, 0.f);
        float v1 = fmaxf(acc[i][j][1] + bb.y, 0.f);
        float v2 = fmaxf(acc[i][j][2] + bb.z, 0.f);
        float v3 = fmaxf(acc[i][j][3] + bb.w, 0.f);
        uint2 o; o.x = pack2(v0, v1); o.y = pack2(v2, v3);
        *(uint2*)(Y + (size_t)r * 128 + c0) = o;
      }
    }
  }
}

// fused1 y=0: Q = (relu(spmm_a(A)·Wa1^T + ba1))·Wo0^T   (B never materialized)
// fused1 y=1: D = relu(spmm_b(C)·Wb1^T + bb1)           (B2 never materialized)
__global__ __launch_bounds__(256, 4) void fused1_kernel(
    const int* __restrict__ rpa, const int* __restrict__ cola,
    const float* __restrict__ vala, const unsigned short* __restrict__ A,
    const unsigned short* __restrict__ Wa1, const float* __restrict__ ba1,
    const unsigned short* __restrict__ Wo0, unsigned short* __restrict__ Q,
    const int* __restrict__ rpb, const int* __restrict__ colb,
    const float* __restrict__ valb, const unsigned short* __restrict__ C,
    const unsigned short* __restrict__ Wb1, const float* __restrict__ bb1,
    unsigned short* __restrict__ D, int n)
{
  __shared__ unsigned short Xs[128 * LDXP];
  const int tid = threadIdx.x;
  const int lane = tid & 63;
  const int wave = tid >> 6;
  const int wm = wave >> 1;
  const int wn = wave & 1;
  const int l15 = lane & 15;
  const int quad = lane >> 4;
  const int row0 = blockIdx.x * 128;

  if (blockIdx.y == 0) {
    // ---- branch a: spmm -> relu GEMM -> GEMM -> Q ----
    spmm_tile_to_lds(rpa, cola, vala, A, Xs, n, row0);
    __syncthreads();

    floatx4 acc1[4][4];
#pragma unroll
    for (int i = 0; i < 4; ++i)
#pragma unroll
      for (int j = 0; j < 4; ++j) acc1[i][j] = (floatx4){0.f, 0.f, 0.f, 0.f};
    mfma_phase<4>(Wa1, 128, Xs, wm, wn, l15, quad, acc1);
    __syncthreads();   // all reads of Xs done before overwrite

    // A2 = relu(acc1 + ba1) -> Xs (bf16)
#pragma unroll
    for (int i = 0; i < 4; ++i) {
      int r2 = wm * 64 + i * 16 + l15;
#pragma unroll
      for (int j = 0; j < 4; ++j) {
        int c2 = wn * 64 + j * 16 + quad * 4;
        float4 bb = *(const float4*)(ba1 + c2);
        float v0 = fmaxf(acc1[i][j][0] + bb.x, 0.f);
        float v1 = fmaxf(acc1[i][j][1] + bb.y, 0.f);
        float v2 = fmaxf(acc1[i][j][2] + bb.z, 0.f);
        float v3 = fmaxf(acc1[i][j][3] + bb.w, 0.f);
        uint2 o; o.x = pack2(v0, v1); o.y = pack2(v2, v3);
        *(uint2*)(Xs + r2 * LDXP + c2) = o;
      }
    }
    __syncthreads();

    floatx4 acc2[4][2];
#pragma unroll
    for (int i = 0; i < 4; ++i)
#pragma unroll
      for (int j = 0; j < 2; ++j) acc2[i][j] = (floatx4){0.f, 0.f, 0.f, 0.f};
    mfma_phase<2>(Wo0, 128, Xs, wm, wn, l15, quad, acc2);

#pragma unroll
    for (int i = 0; i < 4; ++i) {
      int r = row0 + wm * 64 + i * 16 + l15;
      if (r >= n) continue;
#pragma unroll
      for (int j = 0; j < 2; ++j) {
        int c0 = wn * 32 + j * 16 + quad * 4;
        uint2 o;
        o.x = pack2(acc2[i][j][0], acc2[i][j][1]);
        o.y = pack2(acc2[i][j][2], acc2[i][j][3]);
        *(uint2*)(Q + (size_t)r * 64 + c0) = o;
      }
    }
  } else {
    // ---- branch b: spmm -> relu GEMM -> D ----
    spmm_tile_to_lds(rpb, colb, valb, C, Xs, n, row0);
    __syncthreads();

    floatx4 acc[4][4];
#pragma unroll
    for (int i = 0; i < 4; ++i)
#pragma unroll
      for (int j = 0; j < 4; ++j) acc[i][j] = (floatx4){0.f, 0.f, 0.f, 0.f};
    mfma_phase<4>(Wb1, 128, Xs, wm, wn, l15, quad, acc);

#pragma unroll
    for (int i = 0; i < 4; ++i) {
      int r = row0 + wm * 64 + i * 16 + l15;
      if (r >= n) continue;
#pragma unroll
      for (int j = 0; j < 4; ++j) {
        int c0 = wn * 64 + j * 16 + quad * 4;
        float4 bb = *(const float4*)(bb1 + c0);
        float v0 = fmaxf(acc[i][j][0] + bb.x, 0.f);
        float v1 = fmaxf(acc[i][j][1] + bb.y, 0.f);
        float v2 = fmaxf(acc[i][j][2] + bb.z, 0.f);
        float v3 = fmaxf(acc[i][j][3] + bb.w, 0.f);
        uint2 o; o.x = pack2(v0, v1); o.y = pack2(v2, v3);
        *(uint2*)(D + (size_t)r * 128 + c0) = o;
      }
    }
  }
}

// fused2: out = relu(C·Wm0 + D·Wm1 + spmm_b(D)·Wm2 + bm)·Wo1^T + bo + spmm_a(Q)
// (g2, A3, Pout all stay in LDS/registers; Pout written straight to out first)
__global__ __launch_bounds__(256, 4) void fused2_kernel(
    const int* __restrict__ rpb, const int* __restrict__ colb,
    const float* __restrict__ valb, const unsigned short* __restrict__ D,
    const int* __restrict__ rpa, const int* __restrict__ cola,
    const float* __restrict__ vala, const unsigned short* __restrict__ Q,
    const unsigned short* __restrict__ C,
    const unsigned short* __restrict__ Wm, const float* __restrict__ bm,
    const unsigned short* __restrict__ Wo1, const float* __restrict__ bo,
    float* __restrict__ out, int n)
{
  __shared__ unsigned short Xs[128 * LDXP];
  const int tid = threadIdx.x;
  const int lane = tid & 63;
  const int wave = tid >> 6;
  const int wm = wave >> 1;
  const int wn = wave & 1;
  const int l15 = lane & 15;
  const int quad = lane >> 4;
  const int row0 = blockIdx.x * 128;
  const int c8 = (tid & 15) * 8;
  const int rloc = tid >> 4;

  // Pout = spmm_a(Q) for this block's rows, written directly to out (f32).
  spmm_tile64_to_out(rpa, cola, vala, Q, out, n, row0);

  // g2 tile = spmm_b(D) -> LDS
  spmm_tile_to_lds(rpb, colb, valb, D, Xs, n, row0);
  __syncthreads();

  floatx4 acc[4][4];
#pragma unroll
  for (int i = 0; i < 4; ++i)
#pragma unroll
    for (int j = 0; j < 4; ++j) acc[i][j] = (floatx4){0.f, 0.f, 0.f, 0.f};

  mfma_phase<4>(Wm + 256, 384, Xs, wm, wn, l15, quad, acc);   // g2·Wm2
  __syncthreads();
  stage_bf16(C, Xs, row0, n, rloc, c8);
  __syncthreads();
  mfma_phase<4>(Wm, 384, Xs, wm, wn, l15, quad, acc);         // g0·Wm0
  __syncthreads();
  stage_bf16(D, Xs, row0, n, rloc, c8);
  __syncthreads();
  mfma_phase<4>(Wm + 128, 384, Xs, wm, wn, l15, quad, acc);   // g1·Wm1
  __syncthreads();

  // A3 = relu(acc + bm) -> Xs (bf16)
#pragma unroll
  for (int i = 0; i < 4; ++i) {
    int r2 = wm * 64 + i * 16 + l15;
#pragma unroll
    for (int j = 0; j < 4; ++j) {
      int c2 = wn * 64 + j * 16 + quad * 4;
      float4 bb = *(const float4*)(bm + c2);
      float v0 = fmaxf(acc[i][j][0] + bb.x, 0.f);
      float v1 = fmaxf(acc[i][j][1] + bb.y, 0.f);
      float v2 = fmaxf(acc[i][j][2] + bb.z, 0.f);
      float v3 = fmaxf(acc[i][j][3] + bb.w, 0.f);
      uint2 o; o.x = pack2(v0, v1); o.y = pack2(v2, v3);
      *(uint2*)(Xs + r2 * LDXP + c2) = o;
    }
  }
  __syncthreads();

  floatx4 acc2[4][2];
#pragma unroll
  for (int i = 0; i < 4; ++i)
#pragma unroll
    for (int j = 0; j < 2; ++j) acc2[i][j] = (floatx4){0.f, 0.f, 0.f, 0.f};
  mfma_phase<2>(Wo1, 128, Xs, wm, wn, l15, quad, acc2);

  // out = acc2 + bo + out(previously written Pout)
#pragma unroll
  for (int i = 0; i < 4; ++i) {
    int r = row0 + wm * 64 + i * 16 + l15;
    if (r >= n) continue;
#pragma unroll
    for (int j = 0; j < 2; ++j) {
      int c0 = wn * 32 + j * 16 + quad * 4;
      float4 bb = *(const float4*)(bo + c0);
      float4 pv = *(const float4*)(out + (size_t)r * 64 + c0);
      float4 o;
      o.x = acc2[i][j][0] + bb.x + pv.x;
      o.y = acc2[i][j][1] + bb.y + pv.y;
      o.z = acc2[i][j][2] + bb.z + pv.z;
      o.w = acc2[i][j][3] + bb.w + pv.w;
      *(float4*)(out + (size_t)r * 64 + c0) = o;
    }
  }
}

extern "C" void kernel_launch(void* const* d_in, const int* in_sizes, int n_in,
                              void* d_out, int out_size, void* d_ws, size_t ws_size,
                              hipStream_t stream)
{
  const float* x     = (const float*)d_in[0];
  const int*   row_a = (const int*)d_in[1];
  const int*   col_a = (const int*)d_in[2];
  const float* val_a = (const float*)d_in[3];
  const int*   row_b = (const int*)d_in[4];
  const int*   col_b = (const int*)d_in[5];
  const float* val_b = (const float*)d_in[6];
  const float* Wa0 = (const float*)d_in[7];  const float* ba0 = (const float*)d_in[8];
  const float* Wa1 = (const float*)d_in[9];  const float* ba1 = (const float*)d_in[10];
  const float* Wb0 = (const float*)d_in[11]; const float* bb0 = (const float*)d_in[12];
  const float* Wb1 = (const float*)d_in[13]; const float* bb1 = (const float*)d_in[14];
  const float* Wm  = (const float*)d_in[15]; const float* bm  = (const float*)d_in[16];
  const float* Wo  = (const float*)d_in[17]; const float* bo  = (const float*)d_in[18];
  float* out = (float*)d_out;

  const int n = in_sizes[0] / 128;   // 50000
  const int E = in_sizes[1];         // 800000

  char* ws = (char*)d_ws;
  size_t off = 0;
  auto alloc = [&](size_t bytes) {
    void* p = ws + off;
    off = (off + bytes + 255) & ~(size_t)255;
    return p;
  };
  int* rpa = (int*)alloc((size_t)(n + 1) * sizeof(int));
  int* rpb = (int*)alloc((size_t)(n + 1) * sizeof(int));
  unsigned short* Wcat = (unsigned short*)alloc(131072 * sizeof(unsigned short));
  const size_t slab = (size_t)n * 128 * sizeof(unsigned short);
  unsigned short* A = (unsigned short*)alloc(slab);   // relu(x Wa0 + ba0)
  unsigned short* C = (unsigned short*)alloc(slab);   // g0
  unsigned short* D = (unsigned short*)alloc(slab);   // g1
  unsigned short* Q = (unsigned short*)alloc((size_t)n * 64 * sizeof(unsigned short));

  const unsigned short* Wa0b = Wcat;
  const unsigned short* Wa1b = Wcat + 16384;
  const unsigned short* Wb0b = Wcat + 32768;
  const unsigned short* Wb1b = Wcat + 49152;
  const unsigned short* Wmb  = Wcat + 65536;   // [128, 384]
  const unsigned short* Wo0b = Wcat + 114688;
  const unsigned short* Wo1b = Wcat + 122880;

  dim3 blk(256);
  dim3 g_setup((n + 1 + 255) / 256, 3);
  dim3 g_lin((n + 127) / 128);
  dim3 g_f1((n + 127) / 128, 2);

  setup_kernel<<<g_setup, blk, 0, stream>>>(row_a, row_b, E, n, rpa, rpb,
                                            Wa0, Wa1, Wb0, Wb1, Wm, Wo, Wcat);

  // A = relu(x Wa0^T + ba0), C = relu(x Wb0^T + bb0)
  gemm_dual_f32_kernel<<<g_lin, blk, 0, stream>>>(x, Wa0b, Wb0b, ba0, bb0, A, C, n);

  // fused1: Q (branch a, spmm+chain) || D (branch b, spmm+g1)
  fused1_kernel<<<g_f1, blk, 0, stream>>>(
      rpa, col_a, val_a, A, Wa1b, ba1, Wo0b, Q,
      rpb, col_b, val_b, C, Wb1b, bb1, D, n);

  // fused2: out = relu(g0 Wm0 + g1 Wm1 + spmm_b(D) Wm2 + bm) Wo1^T + bo + spmm_a(Q)
  fused2_kernel<<<g_lin, blk, 0, stream>>>(
      rpb, col_b, val_b, D,
      rpa, col_a, val_a, Q,
      C, Wmb, bm, Wo1b, bo, out, n);
}

// Round 7
// 293.656 us; speedup vs baseline: 1.3854x; 1.1227x over previous
//
#include <hip/hip_runtime.h>

// ---------------------------------------------------------------------------
// DualGCN v9: v5 SpMM structure (proven 2.5-3 TB/s) + GEMM-side merges only.
//   - spmm_dual128 / spmm_mixed: v5 verbatim (fine-grid, 16 rows/block).
//   - chain_g1: chain(Q) + g1(D) in one launch (independent, v7-proven).
//   - wm_final: relu([g0,g1,g2]Wm^T+bm)·Wo1^T + bo + Pout in ONE kernel
//     (A3 tile lives in LDS; A3 slab + one launch eliminated). Pure GEMM
//     chain -> no SpMM occupancy coupling (the v7/v8 failure mode).
// 6 launches. N=50000, E=800000, H=128, OUT=64.
// ---------------------------------------------------------------------------

typedef short short8 __attribute__((ext_vector_type(8)));
typedef float floatx4 __attribute__((ext_vector_type(4)));

#define LDXP 136   // padded LDS row stride (bf16 units)

__device__ inline unsigned short f2bf(float f) {
  unsigned u = __builtin_bit_cast(unsigned, f);
  u += 0x7fffu + ((u >> 16) & 1u);      // round-to-nearest-even
  return (unsigned short)(u >> 16);
}
__device__ inline unsigned pack2(float a, float b) {
  return (unsigned)f2bf(a) | ((unsigned)f2bf(b) << 16);
}
__device__ inline float bf_lo(unsigned w) {
  return __builtin_bit_cast(float, w << 16);
}
__device__ inline float bf_hi(unsigned w) {
  return __builtin_bit_cast(float, w & 0xffff0000u);
}

// y=0: rowptr for graph a; y=1: rowptr for graph b; y=2: convert weights.
// Wo de-interleaved into Wo0 = Wo[:, :128] and Wo1 = Wo[:, 128:].
__global__ __launch_bounds__(256) void setup_kernel(
    const int* __restrict__ rowA, const int* __restrict__ rowB,
    int E, int n, int* __restrict__ rpa, int* __restrict__ rpb,
    const float* __restrict__ Wa0, const float* __restrict__ Wa1,
    const float* __restrict__ Wb0, const float* __restrict__ Wb1,
    const float* __restrict__ Wm,  const float* __restrict__ Wo,
    unsigned short* __restrict__ Wout)
{
  if (blockIdx.y == 2) {
    for (int i = blockIdx.x * 256 + threadIdx.x; i < 131072; i += gridDim.x * 256) {
      float v;
      if      (i < 16384)  v = Wa0[i];
      else if (i < 32768)  v = Wa1[i - 16384];
      else if (i < 49152)  v = Wb0[i - 32768];
      else if (i < 65536)  v = Wb1[i - 49152];
      else if (i < 114688) v = Wm[i - 65536];
      else {
        int o = i - 114688;           // [0, 16384)
        int half = o >> 13;           // 0 -> Wo0, 1 -> Wo1
        int idx = o & 8191;
        int r = idx >> 7, c = idx & 127;
        v = Wo[r * 256 + half * 128 + c];
      }
      Wout[i] = f2bf(v);
    }
    return;
  }
  int i = blockIdx.x * blockDim.x + threadIdx.x;
  if (i > n) return;
  const int* row = blockIdx.y ? rowB : rowA;
  int* rp = blockIdx.y ? rpb : rpa;
  int lo = 0, hi = E;
  while (lo < hi) {
    int mid = (lo + hi) >> 1;
    if (row[mid] < i) lo = mid + 1; else hi = mid;
  }
  rp[i] = lo;
}

// ---------------------------------------------------------------------------
// SpMM row body (v5, proven): Y[g,:] = sum_e val[e] * X[col[e],:]
// WIDTH bf16 features; WIDTH/8 lanes per row, 16 B gather per lane.
// Depth-2 software pipeline: col/val prefetched 2 batches ahead.
// ---------------------------------------------------------------------------
template <int WIDTH, bool OUTF32>
__device__ __forceinline__ void spmm_rows(
    const int* __restrict__ rowptr, const int* __restrict__ col,
    const float* __restrict__ val, const unsigned short* __restrict__ X,
    void* __restrict__ Yv, int n, int bx)
{
  constexpr int LPR = WIDTH / 8;        // lanes per row
  constexpr int GPB = 256 / LPR;        // row-groups per block
  int g = bx * GPB + ((int)threadIdx.x / LPR);
  int lane = threadIdx.x & (LPR - 1);
  if (g >= n) return;
  int e0 = rowptr[g], e1 = rowptr[g + 1];

  float a0 = 0.f, a1 = 0.f, a2 = 0.f, a3 = 0.f;
  float a4 = 0.f, a5 = 0.f, a6 = 0.f, a7 = 0.f;
  const size_t loff = (size_t)lane * 8;

  auto gat = [&](int c) -> uint4 {
    return *(const uint4*)(X + (size_t)c * WIDTH + loff);
  };
  auto fma1 = [&](float v, uint4 w) {
    a0 = fmaf(v, bf_lo(w.x), a0); a1 = fmaf(v, bf_hi(w.x), a1);
    a2 = fmaf(v, bf_lo(w.y), a2); a3 = fmaf(v, bf_hi(w.y), a3);
    a4 = fmaf(v, bf_lo(w.z), a4); a5 = fmaf(v, bf_hi(w.z), a5);
    a6 = fmaf(v, bf_lo(w.w), a6); a7 = fmaf(v, bf_hi(w.w), a7);
  };
  auto accum = [&](int c, float v) { fma1(v, gat(c)); };

  int e = e0;
  int epro = (e0 + 3) & ~3;             // align to 4 for vector col/val loads
  if (epro > e1) epro = e1;
  for (; e < epro; ++e) accum(col[e], val[e]);

  int nb = (e1 - e) >> 2;               // full 4-edge batches
  if (nb > 0) {
    int4   cA = *(const int4*)(col + e);
    float4 vA = *(const float4*)(val + e);
    int4   cB = cA; float4 vB = vA;
    if (nb > 1) { cB = *(const int4*)(col + e + 4); vB = *(const float4*)(val + e + 4); }
    uint4 w0 = gat(cA.x), w1 = gat(cA.y), w2 = gat(cA.z), w3 = gat(cA.w);
    for (int t = 0; t < nb - 1; ++t) {
      int4 cC = cB; float4 vC = vB;
      if (t + 2 < nb) {
        cC = *(const int4*)(col + e + 4 * (t + 2));
        vC = *(const float4*)(val + e + 4 * (t + 2));
      }
      uint4 u0 = gat(cB.x), u1 = gat(cB.y), u2 = gat(cB.z), u3 = gat(cB.w);
      fma1(vA.x, w0); fma1(vA.y, w1); fma1(vA.z, w2); fma1(vA.w, w3);
      vA = vB; vB = vC; cB = cC;
      w0 = u0; w1 = u1; w2 = u2; w3 = u3;
    }
    fma1(vA.x, w0); fma1(vA.y, w1); fma1(vA.z, w2); fma1(vA.w, w3);
    e += nb * 4;
  }
  for (; e < e1; ++e) accum(col[e], val[e]);

  if (OUTF32) {
    float* Y = (float*)Yv;
    float4 o0; o0.x = a0; o0.y = a1; o0.z = a2; o0.w = a3;
    float4 o1; o1.x = a4; o1.y = a5; o1.z = a6; o1.w = a7;
    *(float4*)(Y + (size_t)g * WIDTH + lane * 8) = o0;
    *(float4*)(Y + (size_t)g * WIDTH + lane * 8 + 4) = o1;
  } else {
    uint4 o;
    o.x = pack2(a0, a1); o.y = pack2(a2, a3);
    o.z = pack2(a4, a5); o.w = pack2(a6, a7);
    *(uint4*)((unsigned short*)Yv + (size_t)g * WIDTH + loff) = o;
  }
}

// y=0: graph a, Xa->Ya; y=1: graph b, Xb->Yb (both 128-wide, bf16 out)
__global__ __launch_bounds__(256) void spmm_dual128_kernel(
    const int* __restrict__ rpa, const int* __restrict__ cola,
    const float* __restrict__ vala, const unsigned short* __restrict__ Xa,
    unsigned short* __restrict__ Ya,
    const int* __restrict__ rpb, const int* __restrict__ colb,
    const float* __restrict__ valb, const unsigned short* __restrict__ Xb,
    unsigned short* __restrict__ Yb, int n)
{
  if (blockIdx.y == 0)
    spmm_rows<128, false>(rpa, cola, vala, Xa, Ya, n, blockIdx.x);
  else
    spmm_rows<128, false>(rpb, colb, valb, Xb, Yb, n, blockIdx.x);
}

// y=0: graph b 128-wide D->Yb (bf16); y=1: graph a 64-wide Q->Pout (f32)
__global__ __launch_bounds__(256) void spmm_mixed_kernel(
    const int* __restrict__ rpb, const int* __restrict__ colb,
    const float* __restrict__ valb, const unsigned short* __restrict__ D,
    unsigned short* __restrict__ Yb,
    const int* __restrict__ rpa, const int* __restrict__ cola,
    const float* __restrict__ vala, const unsigned short* __restrict__ Q,
    float* __restrict__ Pout, int n)
{
  if (blockIdx.y == 0)
    spmm_rows<128, false>(rpb, colb, valb, D, Yb, n, blockIdx.x);
  else
    spmm_rows<64, true>(rpa, cola, vala, Q, Pout, n, blockIdx.x);
}

// ---------------------------------------------------------------------------
// GEMM building blocks. Block: 256 thr = 4 waves 2x2; tile 128 rows x HOUT.
// X operand in LDS (padded); W fragments read from global (L1/L2-hot).
// ---------------------------------------------------------------------------
__device__ inline void stage_bf16(const unsigned short* __restrict__ Xp,
                                  unsigned short* Xs, int row0, int n,
                                  int rloc, int c8)
{
#pragma unroll
  for (int p = 0; p < 8; ++p) {
    int r = p * 16 + rloc;
    int gr = row0 + r;
    uint4 v = make_uint4(0u, 0u, 0u, 0u);
    if (gr < n) v = *(const uint4*)(Xp + (size_t)gr * 128 + c8);
    *(uint4*)(Xs + r * LDXP + c8) = v;
  }
}

template <int NT>
__device__ inline void mfma_phase(const unsigned short* __restrict__ W, int wld,
                                  const unsigned short* Xs,
                                  int wm, int wn, int l15, int quad,
                                  floatx4 (&acc)[4][NT])
{
#pragma unroll
  for (int k0 = 0; k0 < 128; k0 += 32) {
    const int ko = k0 + quad * 8;
    short8 aW[NT], bX[4];
#pragma unroll
    for (int j = 0; j < NT; ++j)
      aW[j] = *(const short8*)(W + (size_t)(wn * (16 * NT) + j * 16 + l15) * wld + ko);
#pragma unroll
    for (int i = 0; i < 4; ++i)
      bX[i] = *(const short8*)(Xs + (wm * 64 + i * 16 + l15) * LDXP + ko);
#pragma unroll
    for (int i = 0; i < 4; ++i)
#pragma unroll
      for (int j = 0; j < NT; ++j)
        acc[i][j] = __builtin_amdgcn_mfma_f32_16x16x32_bf16(aW[j], bX[i], acc[i][j], 0, 0, 0);
  }
}

// ---------------------------------------------------------------------------
// Kernels
// ---------------------------------------------------------------------------

// A = relu(x@W1.T+b1), C = relu(x@W2.T+b2) from fp32 x, shared X staging.
__global__ __launch_bounds__(256, 2) void gemm_dual_f32_kernel(
    const float* __restrict__ X, const unsigned short* __restrict__ W1,
    const unsigned short* __restrict__ W2, const float* __restrict__ b1,
    const float* __restrict__ b2, unsigned short* __restrict__ Y1,
    unsigned short* __restrict__ Y2, int n)
{
  constexpr int NT = 4;  // HOUT = 128
  __shared__ unsigned short Xs[128 * LDXP];
  const int tid = threadIdx.x;
  const int lane = tid & 63;
  const int wave = tid >> 6;
  const int wm = wave >> 1;
  const int wn = wave & 1;
  const int l15 = lane & 15;
  const int quad = lane >> 4;
  const int row0 = blockIdx.x * 128;
  const int c8 = (tid & 15) * 8;
  const int rloc = tid >> 4;

#pragma unroll
  for (int p = 0; p < 8; ++p) {
    int r = p * 16 + rloc;
    int gr = row0 + r;
    uint4 o = make_uint4(0u, 0u, 0u, 0u);
    if (gr < n) {
      float4 f0 = *(const float4*)(X + (size_t)gr * 128 + c8);
      float4 f1 = *(const float4*)(X + (size_t)gr * 128 + c8 + 4);
      o.x = pack2(f0.x, f0.y); o.y = pack2(f0.z, f0.w);
      o.z = pack2(f1.x, f1.y); o.w = pack2(f1.z, f1.w);
    }
    *(uint4*)(Xs + r * LDXP + c8) = o;
  }
  __syncthreads();

  for (int s = 0; s < 2; ++s) {
    const unsigned short* W = s ? W2 : W1;
    const float* b = s ? b2 : b1;
    unsigned short* Y = s ? Y2 : Y1;
    floatx4 acc[4][NT];
#pragma unroll
    for (int i = 0; i < 4; ++i)
#pragma unroll
      for (int j = 0; j < NT; ++j) acc[i][j] = (floatx4){0.f, 0.f, 0.f, 0.f};
    mfma_phase<NT>(W, 128, Xs, wm, wn, l15, quad, acc);
#pragma unroll
    for (int i = 0; i < 4; ++i) {
      int r = row0 + wm * 64 + i * 16 + l15;
      if (r >= n) continue;
#pragma unroll
      for (int j = 0; j < NT; ++j) {
        int c0 = wn * 64 + j * 16 + quad * 4;
        float4 bb = *(const float4*)(b + c0);
        float v0 = fmaxf(acc[i][j][0] + bb.x, 0.f);
        float v1 = fmaxf(acc[i][j][1] + bb.y, 0.f);
        float v2 = fmaxf(acc[i][j][2] + bb.z, 0.f);
        float v3 = fmaxf(acc[i][j][3] + bb.w, 0.f);
        uint2 o; o.x = pack2(v0, v1); o.y = pack2(v2, v3);
        *(uint2*)(Y + (size_t)r * 128 + c0) = o;
      }
    }
  }
}

// y=0: Q = (relu(B·Wa1^T+ba1))·Wo0^T (chained through LDS)
// y=1: D = relu(B2·Wb1^T+bb1)
__global__ __launch_bounds__(256, 2) void chain_g1_kernel(
    const unsigned short* __restrict__ B, const unsigned short* __restrict__ Wa1,
    const float* __restrict__ ba1, const unsigned short* __restrict__ Wo0,
    unsigned short* __restrict__ Q,
    const unsigned short* __restrict__ B2, const unsigned short* __restrict__ Wb1,
    const float* __restrict__ bb1, unsigned short* __restrict__ D, int n)
{
  __shared__ unsigned short Xs[128 * LDXP];
  const int tid = threadIdx.x;
  const int lane = tid & 63;
  const int wave = tid >> 6;
  const int wm = wave >> 1;
  const int wn = wave & 1;
  const int l15 = lane & 15;
  const int quad = lane >> 4;
  const int row0 = blockIdx.x * 128;
  const int c8 = (tid & 15) * 8;
  const int rloc = tid >> 4;

  if (blockIdx.y == 0) {
    stage_bf16(B, Xs, row0, n, rloc, c8);
    __syncthreads();

    floatx4 acc1[4][4];
#pragma unroll
    for (int i = 0; i < 4; ++i)
#pragma unroll
      for (int j = 0; j < 4; ++j) acc1[i][j] = (floatx4){0.f, 0.f, 0.f, 0.f};
    mfma_phase<4>(Wa1, 128, Xs, wm, wn, l15, quad, acc1);
    __syncthreads();   // all stage-1 reads of Xs done before overwrite

    // A2 = relu(acc1 + ba1) -> Xs (bf16)
#pragma unroll
    for (int i = 0; i < 4; ++i) {
      int r2 = wm * 64 + i * 16 + l15;
#pragma unroll
      for (int j = 0; j < 4; ++j) {
        int c2 = wn * 64 + j * 16 + quad * 4;
        float4 bb = *(const float4*)(ba1 + c2);
        float v0 = fmaxf(acc1[i][j][0] + bb.x, 0.f);
        float v1 = fmaxf(acc1[i][j][1] + bb.y, 0.f);
        float v2 = fmaxf(acc1[i][j][2] + bb.z, 0.f);
        float v3 = fmaxf(acc1[i][j][3] + bb.w, 0.f);
        uint2 o; o.x = pack2(v0, v1); o.y = pack2(v2, v3);
        *(uint2*)(Xs + r2 * LDXP + c2) = o;
      }
    }
    __syncthreads();

    floatx4 acc2[4][2];
#pragma unroll
    for (int i = 0; i < 4; ++i)
#pragma unroll
      for (int j = 0; j < 2; ++j) acc2[i][j] = (floatx4){0.f, 0.f, 0.f, 0.f};
    mfma_phase<2>(Wo0, 128, Xs, wm, wn, l15, quad, acc2);

#pragma unroll
    for (int i = 0; i < 4; ++i) {
      int r = row0 + wm * 64 + i * 16 + l15;
      if (r >= n) continue;
#pragma unroll
      for (int j = 0; j < 2; ++j) {
        int c0 = wn * 32 + j * 16 + quad * 4;
        uint2 o;
        o.x = pack2(acc2[i][j][0], acc2[i][j][1]);
        o.y = pack2(acc2[i][j][2], acc2[i][j][3]);
        *(uint2*)(Q + (size_t)r * 64 + c0) = o;
      }
    }
  } else {
    stage_bf16(B2, Xs, row0, n, rloc, c8);
    __syncthreads();

    floatx4 acc[4][4];
#pragma unroll
    for (int i = 0; i < 4; ++i)
#pragma unroll
      for (int j = 0; j < 4; ++j) acc[i][j] = (floatx4){0.f, 0.f, 0.f, 0.f};
    mfma_phase<4>(Wb1, 128, Xs, wm, wn, l15, quad, acc);

#pragma unroll
    for (int i = 0; i < 4; ++i) {
      int r = row0 + wm * 64 + i * 16 + l15;
      if (r >= n) continue;
#pragma unroll
      for (int j = 0; j < 4; ++j) {
        int c0 = wn * 64 + j * 16 + quad * 4;
        float4 bb = *(const float4*)(bb1 + c0);
        float v0 = fmaxf(acc[i][j][0] + bb.x, 0.f);
        float v1 = fmaxf(acc[i][j][1] + bb.y, 0.f);
        float v2 = fmaxf(acc[i][j][2] + bb.z, 0.f);
        float v3 = fmaxf(acc[i][j][3] + bb.w, 0.f);
        uint2 o; o.x = pack2(v0, v1); o.y = pack2(v2, v3);
        *(uint2*)(D + (size_t)r * 128 + c0) = o;
      }
    }
  }
}

// out = relu(C·Wm0 + D·Wm1 + G2·Wm2 + bm)·Wo1^T + bo + Pout  (A3 in LDS only)
__global__ __launch_bounds__(256, 2) void wm_final_kernel(
    const unsigned short* __restrict__ C, const unsigned short* __restrict__ D,
    const unsigned short* __restrict__ G2,
    const unsigned short* __restrict__ Wm, const float* __restrict__ bm,
    const unsigned short* __restrict__ Wo1, const float* __restrict__ bo,
    const float* __restrict__ Pout, float* __restrict__ out, int n)
{
  __shared__ unsigned short Xs[128 * LDXP];
  const int tid = threadIdx.x;
  const int lane = tid & 63;
  const int wave = tid >> 6;
  const int wm_ = wave >> 1;
  const int wn = wave & 1;
  const int l15 = lane & 15;
  const int quad = lane >> 4;
  const int row0 = blockIdx.x * 128;
  const int c8 = (tid & 15) * 8;
  const int rloc = tid >> 4;

  floatx4 acc[4][4];
#pragma unroll
  for (int i = 0; i < 4; ++i)
#pragma unroll
    for (int j = 0; j < 4; ++j) acc[i][j] = (floatx4){0.f, 0.f, 0.f, 0.f};

  const unsigned short* Xp[3] = {C, D, G2};
#pragma unroll
  for (int s = 0; s < 3; ++s) {
    if (s) __syncthreads();
    stage_bf16(Xp[s], Xs, row0, n, rloc, c8);
    __syncthreads();
    mfma_phase<4>(Wm + s * 128, 384, Xs, wm_, wn, l15, quad, acc);
  }
  __syncthreads();   // all K=384 reads done before A3 overwrite

  // A3 = relu(acc + bm) -> Xs (bf16)
#pragma unroll
  for (int i = 0; i < 4; ++i) {
    int r2 = wm_ * 64 + i * 16 + l15;
#pragma unroll
    for (int j = 0; j < 4; ++j) {
      int c2 = wn * 64 + j * 16 + quad * 4;
      float4 bb = *(const float4*)(bm + c2);
      float v0 = fmaxf(acc[i][j][0] + bb.x, 0.f);
      float v1 = fmaxf(acc[i][j][1] + bb.y, 0.f);
      float v2 = fmaxf(acc[i][j][2] + bb.z, 0.f);
      float v3 = fmaxf(acc[i][j][3] + bb.w, 0.f);
      uint2 o; o.x = pack2(v0, v1); o.y = pack2(v2, v3);
      *(uint2*)(Xs + r2 * LDXP + c2) = o;
    }
  }
  __syncthreads();

  floatx4 acc2[4][2];
#pragma unroll
  for (int i = 0; i < 4; ++i)
#pragma unroll
    for (int j = 0; j < 2; ++j) acc2[i][j] = (floatx4){0.f, 0.f, 0.f, 0.f};
  mfma_phase<2>(Wo1, 128, Xs, wm_, wn, l15, quad, acc2);

#pragma unroll
  for (int i = 0; i < 4; ++i) {
    int r = row0 + wm_ * 64 + i * 16 + l15;
    if (r >= n) continue;
#pragma unroll
    for (int j = 0; j < 2; ++j) {
      int c0 = wn * 32 + j * 16 + quad * 4;
      float4 bb = *(const float4*)(bo + c0);
      float4 pv = *(const float4*)(Pout + (size_t)r * 64 + c0);
      float4 o;
      o.x = acc2[i][j][0] + bb.x + pv.x;
      o.y = acc2[i][j][1] + bb.y + pv.y;
      o.z = acc2[i][j][2] + bb.z + pv.z;
      o.w = acc2[i][j][3] + bb.w + pv.w;
      *(float4*)(out + (size_t)r * 64 + c0) = o;
    }
  }
}

extern "C" void kernel_launch(void* const* d_in, const int* in_sizes, int n_in,
                              void* d_out, int out_size, void* d_ws, size_t ws_size,
                              hipStream_t stream)
{
  const float* x     = (const float*)d_in[0];
  const int*   row_a = (const int*)d_in[1];
  const int*   col_a = (const int*)d_in[2];
  const float* val_a = (const float*)d_in[3];
  const int*   row_b = (const int*)d_in[4];
  const int*   col_b = (const int*)d_in[5];
  const float* val_b = (const float*)d_in[6];
  const float* Wa0 = (const float*)d_in[7];  const float* ba0 = (const float*)d_in[8];
  const float* Wa1 = (const float*)d_in[9];  const float* ba1 = (const float*)d_in[10];
  const float* Wb0 = (const float*)d_in[11]; const float* bb0 = (const float*)d_in[12];
  const float* Wb1 = (const float*)d_in[13]; const float* bb1 = (const float*)d_in[14];
  const float* Wm  = (const float*)d_in[15]; const float* bm  = (const float*)d_in[16];
  const float* Wo  = (const float*)d_in[17]; const float* bo  = (const float*)d_in[18];
  float* out = (float*)d_out;

  const int n = in_sizes[0] / 128;   // 50000
  const int E = in_sizes[1];         // 800000

  char* ws = (char*)d_ws;
  size_t off = 0;
  auto alloc = [&](size_t bytes) {
    void* p = ws + off;
    off = (off + bytes + 255) & ~(size_t)255;
    return p;
  };
  int* rpa = (int*)alloc((size_t)(n + 1) * sizeof(int));
  int* rpb = (int*)alloc((size_t)(n + 1) * sizeof(int));
  unsigned short* Wcat = (unsigned short*)alloc(131072 * sizeof(unsigned short));
  const size_t slab = (size_t)n * 128 * sizeof(unsigned short);
  unsigned short* A  = (unsigned short*)alloc(slab);   // relu(x Wa0 + ba0)
  unsigned short* C  = (unsigned short*)alloc(slab);   // g0
  unsigned short* B  = (unsigned short*)alloc(slab);   // graph-a sp1 out / g2
  unsigned short* B2 = (unsigned short*)alloc(slab);   // graph-b sp1 out
  unsigned short* D  = (unsigned short*)alloc(slab);   // g1
  unsigned short* Q  = (unsigned short*)alloc((size_t)n * 64 * sizeof(unsigned short));
  float* Pout = (float*)alloc((size_t)n * 64 * sizeof(float)); // x_a @ Wo0^T

  const unsigned short* Wa0b = Wcat;
  const unsigned short* Wa1b = Wcat + 16384;
  const unsigned short* Wb0b = Wcat + 32768;
  const unsigned short* Wb1b = Wcat + 49152;
  const unsigned short* Wmb  = Wcat + 65536;   // [128, 384]
  const unsigned short* Wo0b = Wcat + 114688;
  const unsigned short* Wo1b = Wcat + 122880;

  dim3 blk(256);
  dim3 g_setup((n + 1 + 255) / 256, 3);
  dim3 g_lin((n + 127) / 128);
  dim3 g_cg((n + 127) / 128, 2);
  dim3 g_sp2((n + 15) / 16, 2);

  setup_kernel<<<g_setup, blk, 0, stream>>>(row_a, row_b, E, n, rpa, rpb,
                                            Wa0, Wa1, Wb0, Wb1, Wm, Wo, Wcat);

  // A = relu(x Wa0^T + ba0), C = relu(x Wb0^T + bb0)
  gemm_dual_f32_kernel<<<g_lin, blk, 0, stream>>>(x, Wa0b, Wb0b, ba0, bb0, A, C, n);

  // spmm_a(A->B) || spmm_b(C->B2)
  spmm_dual128_kernel<<<g_sp2, blk, 0, stream>>>(
      rpa, col_a, val_a, A, B,
      rpb, col_b, val_b, C, B2, n);

  // chain: Q = relu(B Wa1^T + ba1) Wo0^T  ||  g1: D = relu(B2 Wb1^T + bb1)
  chain_g1_kernel<<<g_cg, blk, 0, stream>>>(
      B, Wa1b, ba1, Wo0b, Q,
      B2, Wb1b, bb1, D, n);

  // g2 = spmm_b(D) -> B  ||  Pout = spmm_a(Q)
  spmm_mixed_kernel<<<g_sp2, blk, 0, stream>>>(
      rpb, col_b, val_b, D, B,
      rpa, col_a, val_a, Q, Pout, n);

  // out = relu(g0 Wm0 + g1 Wm1 + g2 Wm2 + bm) Wo1^T + bo + Pout
  wm_final_kernel<<<g_lin, blk, 0, stream>>>(
      C, D, B, Wmb, bm, Wo1b, bo, Pout, out, n);
}

// Round 8
// 292.628 us; speedup vs baseline: 1.3902x; 1.0035x over previous
//
#include <hip/hip_runtime.h>

// ---------------------------------------------------------------------------
// DualGCN v10: v9 + feature-split 2-phase SpMM gathers.
//   128-wide SpMMs gather in two phases over feature halves (128 B line per
//   edge per phase, 8 lanes/row). Halves the instantaneous L2 line working
//   set -> each line catches ~2x more of its ~16 consumers before eviction.
//   Each phase runs the full v5 depth-2 streaming pipeline (v6's serialized
//   cursor mistake avoided); one __syncthreads between phases.
//   64-wide Q gather stays single-phase (slab already 6.4 MB).
//   GEMMs / structure unchanged from v9 (proven 293.7 us).
// 6 launches. N=50000, E=800000, H=128, OUT=64.
// ---------------------------------------------------------------------------

typedef short short8 __attribute__((ext_vector_type(8)));
typedef float floatx4 __attribute__((ext_vector_type(4)));

#define LDXP 136   // padded LDS row stride (bf16 units)

__device__ inline unsigned short f2bf(float f) {
  unsigned u = __builtin_bit_cast(unsigned, f);
  u += 0x7fffu + ((u >> 16) & 1u);      // round-to-nearest-even
  return (unsigned short)(u >> 16);
}
__device__ inline unsigned pack2(float a, float b) {
  return (unsigned)f2bf(a) | ((unsigned)f2bf(b) << 16);
}
__device__ inline float bf_lo(unsigned w) {
  return __builtin_bit_cast(float, w << 16);
}
__device__ inline float bf_hi(unsigned w) {
  return __builtin_bit_cast(float, w & 0xffff0000u);
}

// y=0: rowptr for graph a; y=1: rowptr for graph b; y=2: convert weights.
// Wo de-interleaved into Wo0 = Wo[:, :128] and Wo1 = Wo[:, 128:].
__global__ __launch_bounds__(256) void setup_kernel(
    const int* __restrict__ rowA, const int* __restrict__ rowB,
    int E, int n, int* __restrict__ rpa, int* __restrict__ rpb,
    const float* __restrict__ Wa0, const float* __restrict__ Wa1,
    const float* __restrict__ Wb0, const float* __restrict__ Wb1,
    const float* __restrict__ Wm,  const float* __restrict__ Wo,
    unsigned short* __restrict__ Wout)
{
  if (blockIdx.y == 2) {
    for (int i = blockIdx.x * 256 + threadIdx.x; i < 131072; i += gridDim.x * 256) {
      float v;
      if      (i < 16384)  v = Wa0[i];
      else if (i < 32768)  v = Wa1[i - 16384];
      else if (i < 49152)  v = Wb0[i - 32768];
      else if (i < 65536)  v = Wb1[i - 49152];
      else if (i < 114688) v = Wm[i - 65536];
      else {
        int o = i - 114688;           // [0, 16384)
        int half = o >> 13;           // 0 -> Wo0, 1 -> Wo1
        int idx = o & 8191;
        int r = idx >> 7, c = idx & 127;
        v = Wo[r * 256 + half * 128 + c];
      }
      Wout[i] = f2bf(v);
    }
    return;
  }
  int i = blockIdx.x * blockDim.x + threadIdx.x;
  if (i > n) return;
  const int* row = blockIdx.y ? rowB : rowA;
  int* rp = blockIdx.y ? rpb : rpa;
  int lo = 0, hi = E;
  while (lo < hi) {
    int mid = (lo + hi) >> 1;
    if (row[mid] < i) lo = mid + 1; else hi = mid;
  }
  rp[i] = lo;
}

// ---------------------------------------------------------------------------
// SpMM gather core (v5 depth-2 pipeline): a[0..7] += val[e]*X[col[e]*STRIDE
// + xoff .. +8]. col/val prefetched 2 batches ahead; 16 B per lane.
// ---------------------------------------------------------------------------
template <int STRIDE>
__device__ __forceinline__ void spmm_gather8(
    int e0, int e1, const int* __restrict__ col, const float* __restrict__ val,
    const unsigned short* __restrict__ X, int xoff, float a[8])
{
  auto gat = [&](int c) -> uint4 {
    return *(const uint4*)(X + (size_t)c * STRIDE + xoff);
  };
  auto fma1 = [&](float v, uint4 w) {
    a[0] = fmaf(v, bf_lo(w.x), a[0]); a[1] = fmaf(v, bf_hi(w.x), a[1]);
    a[2] = fmaf(v, bf_lo(w.y), a[2]); a[3] = fmaf(v, bf_hi(w.y), a[3]);
    a[4] = fmaf(v, bf_lo(w.z), a[4]); a[5] = fmaf(v, bf_hi(w.z), a[5]);
    a[6] = fmaf(v, bf_lo(w.w), a[6]); a[7] = fmaf(v, bf_hi(w.w), a[7]);
  };

  int e = e0;
  int epro = (e0 + 3) & ~3;             // align to 4 for vector col/val loads
  if (epro > e1) epro = e1;
  for (; e < epro; ++e) fma1(val[e], gat(col[e]));

  int nb = (e1 - e) >> 2;               // full 4-edge batches
  if (nb > 0) {
    int4   cA = *(const int4*)(col + e);
    float4 vA = *(const float4*)(val + e);
    int4   cB = cA; float4 vB = vA;
    if (nb > 1) { cB = *(const int4*)(col + e + 4); vB = *(const float4*)(val + e + 4); }
    uint4 w0 = gat(cA.x), w1 = gat(cA.y), w2 = gat(cA.z), w3 = gat(cA.w);
    for (int t = 0; t < nb - 1; ++t) {
      int4 cC = cB; float4 vC = vB;
      if (t + 2 < nb) {
        cC = *(const int4*)(col + e + 4 * (t + 2));
        vC = *(const float4*)(val + e + 4 * (t + 2));
      }
      uint4 u0 = gat(cB.x), u1 = gat(cB.y), u2 = gat(cB.z), u3 = gat(cB.w);
      fma1(vA.x, w0); fma1(vA.y, w1); fma1(vA.z, w2); fma1(vA.w, w3);
      vA = vB; vB = vC; cB = cC;
      w0 = u0; w1 = u1; w2 = u2; w3 = u3;
    }
    fma1(vA.x, w0); fma1(vA.y, w1); fma1(vA.z, w2); fma1(vA.w, w3);
    e += nb * 4;
  }
  for (; e < e1; ++e) fma1(val[e], gat(col[e]));
}

// 2-phase feature-split 128-wide SpMM: 8 lanes/row, 32 rows/block, bf16 out.
// Phase p gathers/writes features [64p, 64p+64). __syncthreads aligns the
// block's waves at the phase boundary (all threads reach it; work guarded).
__device__ __forceinline__ void spmm_rows_phased128(
    const int* __restrict__ rowptr, const int* __restrict__ col,
    const float* __restrict__ val, const unsigned short* __restrict__ X,
    unsigned short* __restrict__ Y, int n, int bx)
{
  const int g = bx * 32 + ((int)threadIdx.x >> 3);
  const int lane = threadIdx.x & 7;
  int e0 = 0, e1 = 0;
  if (g < n) { e0 = rowptr[g]; e1 = rowptr[g + 1]; }

#pragma unroll
  for (int ph = 0; ph < 2; ++ph) {
    float a[8] = {0.f, 0.f, 0.f, 0.f, 0.f, 0.f, 0.f, 0.f};
    spmm_gather8<128>(e0, e1, col, val, X, ph * 64 + lane * 8, a);
    if (g < n) {
      uint4 o;
      o.x = pack2(a[0], a[1]); o.y = pack2(a[2], a[3]);
      o.z = pack2(a[4], a[5]); o.w = pack2(a[6], a[7]);
      *(uint4*)(Y + (size_t)g * 128 + ph * 64 + lane * 8) = o;
    }
    if (ph == 0) __syncthreads();
  }
}

// single-phase 64-wide SpMM (slab already small): 8 lanes/row, f32 out.
__device__ __forceinline__ void spmm_rows64_f32(
    const int* __restrict__ rowptr, const int* __restrict__ col,
    const float* __restrict__ val, const unsigned short* __restrict__ X,
    float* __restrict__ Y, int n, int bx)
{
  const int g = bx * 32 + ((int)threadIdx.x >> 3);
  const int lane = threadIdx.x & 7;
  if (g >= n) return;
  int e0 = rowptr[g], e1 = rowptr[g + 1];
  float a[8] = {0.f, 0.f, 0.f, 0.f, 0.f, 0.f, 0.f, 0.f};
  spmm_gather8<64>(e0, e1, col, val, X, lane * 8, a);
  float4 o0; o0.x = a[0]; o0.y = a[1]; o0.z = a[2]; o0.w = a[3];
  float4 o1; o1.x = a[4]; o1.y = a[5]; o1.z = a[6]; o1.w = a[7];
  *(float4*)(Y + (size_t)g * 64 + lane * 8) = o0;
  *(float4*)(Y + (size_t)g * 64 + lane * 8 + 4) = o1;
}

// y=0: graph a, Xa->Ya; y=1: graph b, Xb->Yb (both phased 128-wide)
__global__ __launch_bounds__(256) void spmm_dual128_kernel(
    const int* __restrict__ rpa, const int* __restrict__ cola,
    const float* __restrict__ vala, const unsigned short* __restrict__ Xa,
    unsigned short* __restrict__ Ya,
    const int* __restrict__ rpb, const int* __restrict__ colb,
    const float* __restrict__ valb, const unsigned short* __restrict__ Xb,
    unsigned short* __restrict__ Yb, int n)
{
  if (blockIdx.y == 0)
    spmm_rows_phased128(rpa, cola, vala, Xa, Ya, n, blockIdx.x);
  else
    spmm_rows_phased128(rpb, colb, valb, Xb, Yb, n, blockIdx.x);
}

// y=0: graph b phased 128-wide D->Yb (bf16); y=1: graph a 64-wide Q->Pout (f32)
__global__ __launch_bounds__(256) void spmm_mixed_kernel(
    const int* __restrict__ rpb, const int* __restrict__ colb,
    const float* __restrict__ valb, const unsigned short* __restrict__ D,
    unsigned short* __restrict__ Yb,
    const int* __restrict__ rpa, const int* __restrict__ cola,
    const float* __restrict__ vala, const unsigned short* __restrict__ Q,
    float* __restrict__ Pout, int n)
{
  if (blockIdx.y == 0)
    spmm_rows_phased128(rpb, colb, valb, D, Yb, n, blockIdx.x);
  else
    spmm_rows64_f32(rpa, cola, vala, Q, Pout, n, blockIdx.x);
}

// ---------------------------------------------------------------------------
// GEMM building blocks (v9 verbatim). Block: 256 thr = 4 waves 2x2;
// tile 128 rows x HOUT. X operand in LDS; W fragments from global.
// ---------------------------------------------------------------------------
__device__ inline void stage_bf16(const unsigned short* __restrict__ Xp,
                                  unsigned short* Xs, int row0, int n,
                                  int rloc, int c8)
{
#pragma unroll
  for (int p = 0; p < 8; ++p) {
    int r = p * 16 + rloc;
    int gr = row0 + r;
    uint4 v = make_uint4(0u, 0u, 0u, 0u);
    if (gr < n) v = *(const uint4*)(Xp + (size_t)gr * 128 + c8);
    *(uint4*)(Xs + r * LDXP + c8) = v;
  }
}

template <int NT>
__device__ inline void mfma_phase(const unsigned short* __restrict__ W, int wld,
                                  const unsigned short* Xs,
                                  int wm, int wn, int l15, int quad,
                                  floatx4 (&acc)[4][NT])
{
#pragma unroll
  for (int k0 = 0; k0 < 128; k0 += 32) {
    const int ko = k0 + quad * 8;
    short8 aW[NT], bX[4];
#pragma unroll
    for (int j = 0; j < NT; ++j)
      aW[j] = *(const short8*)(W + (size_t)(wn * (16 * NT) + j * 16 + l15) * wld + ko);
#pragma unroll
    for (int i = 0; i < 4; ++i)
      bX[i] = *(const short8*)(Xs + (wm * 64 + i * 16 + l15) * LDXP + ko);
#pragma unroll
    for (int i = 0; i < 4; ++i)
#pragma unroll
      for (int j = 0; j < NT; ++j)
        acc[i][j] = __builtin_amdgcn_mfma_f32_16x16x32_bf16(aW[j], bX[i], acc[i][j], 0, 0, 0);
  }
}

// A = relu(x@W1.T+b1), C = relu(x@W2.T+b2) from fp32 x, shared X staging.
__global__ __launch_bounds__(256, 2) void gemm_dual_f32_kernel(
    const float* __restrict__ X, const unsigned short* __restrict__ W1,
    const unsigned short* __restrict__ W2, const float* __restrict__ b1,
    const float* __restrict__ b2, unsigned short* __restrict__ Y1,
    unsigned short* __restrict__ Y2, int n)
{
  constexpr int NT = 4;  // HOUT = 128
  __shared__ unsigned short Xs[128 * LDXP];
  const int tid = threadIdx.x;
  const int lane = tid & 63;
  const int wave = tid >> 6;
  const int wm = wave >> 1;
  const int wn = wave & 1;
  const int l15 = lane & 15;
  const int quad = lane >> 4;
  const int row0 = blockIdx.x * 128;
  const int c8 = (tid & 15) * 8;
  const int rloc = tid >> 4;

#pragma unroll
  for (int p = 0; p < 8; ++p) {
    int r = p * 16 + rloc;
    int gr = row0 + r;
    uint4 o = make_uint4(0u, 0u, 0u, 0u);
    if (gr < n) {
      float4 f0 = *(const float4*)(X + (size_t)gr * 128 + c8);
      float4 f1 = *(const float4*)(X + (size_t)gr * 128 + c8 + 4);
      o.x = pack2(f0.x, f0.y); o.y = pack2(f0.z, f0.w);
      o.z = pack2(f1.x, f1.y); o.w = pack2(f1.z, f1.w);
    }
    *(uint4*)(Xs + r * LDXP + c8) = o;
  }
  __syncthreads();

  for (int s = 0; s < 2; ++s) {
    const unsigned short* W = s ? W2 : W1;
    const float* b = s ? b2 : b1;
    unsigned short* Y = s ? Y2 : Y1;
    floatx4 acc[4][NT];
#pragma unroll
    for (int i = 0; i < 4; ++i)
#pragma unroll
      for (int j = 0; j < NT; ++j) acc[i][j] = (floatx4){0.f, 0.f, 0.f, 0.f};
    mfma_phase<NT>(W, 128, Xs, wm, wn, l15, quad, acc);
#pragma unroll
    for (int i = 0; i < 4; ++i) {
      int r = row0 + wm * 64 + i * 16 + l15;
      if (r >= n) continue;
#pragma unroll
      for (int j = 0; j < NT; ++j) {
        int c0 = wn * 64 + j * 16 + quad * 4;
        float4 bb = *(const float4*)(b + c0);
        float v0 = fmaxf(acc[i][j][0] + bb.x, 0.f);
        float v1 = fmaxf(acc[i][j][1] + bb.y, 0.f);
        float v2 = fmaxf(acc[i][j][2] + bb.z, 0.f);
        float v3 = fmaxf(acc[i][j][3] + bb.w, 0.f);
        uint2 o; o.x = pack2(v0, v1); o.y = pack2(v2, v3);
        *(uint2*)(Y + (size_t)r * 128 + c0) = o;
      }
    }
  }
}

// y=0: Q = (relu(B·Wa1^T+ba1))·Wo0^T (chained through LDS)
// y=1: D = relu(B2·Wb1^T+bb1)
__global__ __launch_bounds__(256, 2) void chain_g1_kernel(
    const unsigned short* __restrict__ B, const unsigned short* __restrict__ Wa1,
    const float* __restrict__ ba1, const unsigned short* __restrict__ Wo0,
    unsigned short* __restrict__ Q,
    const unsigned short* __restrict__ B2, const unsigned short* __restrict__ Wb1,
    const float* __restrict__ bb1, unsigned short* __restrict__ D, int n)
{
  __shared__ unsigned short Xs[128 * LDXP];
  const int tid = threadIdx.x;
  const int lane = tid & 63;
  const int wave = tid >> 6;
  const int wm = wave >> 1;
  const int wn = wave & 1;
  const int l15 = lane & 15;
  const int quad = lane >> 4;
  const int row0 = blockIdx.x * 128;
  const int c8 = (tid & 15) * 8;
  const int rloc = tid >> 4;

  if (blockIdx.y == 0) {
    stage_bf16(B, Xs, row0, n, rloc, c8);
    __syncthreads();

    floatx4 acc1[4][4];
#pragma unroll
    for (int i = 0; i < 4; ++i)
#pragma unroll
      for (int j = 0; j < 4; ++j) acc1[i][j] = (floatx4){0.f, 0.f, 0.f, 0.f};
    mfma_phase<4>(Wa1, 128, Xs, wm, wn, l15, quad, acc1);
    __syncthreads();   // all stage-1 reads of Xs done before overwrite

    // A2 = relu(acc1 + ba1) -> Xs (bf16)
#pragma unroll
    for (int i = 0; i < 4; ++i) {
      int r2 = wm * 64 + i * 16 + l15;
#pragma unroll
      for (int j = 0; j < 4; ++j) {
        int c2 = wn * 64 + j * 16 + quad * 4;
        float4 bb = *(const float4*)(ba1 + c2);
        float v0 = fmaxf(acc1[i][j][0] + bb.x, 0.f);
        float v1 = fmaxf(acc1[i][j][1] + bb.y, 0.f);
        float v2 = fmaxf(acc1[i][j][2] + bb.z, 0.f);
        float v3 = fmaxf(acc1[i][j][3] + bb.w, 0.f);
        uint2 o; o.x = pack2(v0, v1); o.y = pack2(v2, v3);
        *(uint2*)(Xs + r2 * LDXP + c2) = o;
      }
    }
    __syncthreads();

    floatx4 acc2[4][2];
#pragma unroll
    for (int i = 0; i < 4; ++i)
#pragma unroll
      for (int j = 0; j < 2; ++j) acc2[i][j] = (floatx4){0.f, 0.f, 0.f, 0.f};
    mfma_phase<2>(Wo0, 128, Xs, wm, wn, l15, quad, acc2);

#pragma unroll
    for (int i = 0; i < 4; ++i) {
      int r = row0 + wm * 64 + i * 16 + l15;
      if (r >= n) continue;
#pragma unroll
      for (int j = 0; j < 2; ++j) {
        int c0 = wn * 32 + j * 16 + quad * 4;
        uint2 o;
        o.x = pack2(acc2[i][j][0], acc2[i][j][1]);
        o.y = pack2(acc2[i][j][2], acc2[i][j][3]);
        *(uint2*)(Q + (size_t)r * 64 + c0) = o;
      }
    }
  } else {
    stage_bf16(B2, Xs, row0, n, rloc, c8);
    __syncthreads();

    floatx4 acc[4][4];
#pragma unroll
    for (int i = 0; i < 4; ++i)
#pragma unroll
      for (int j = 0; j < 4; ++j) acc[i][j] = (floatx4){0.f, 0.f, 0.f, 0.f};
    mfma_phase<4>(Wb1, 128, Xs, wm, wn, l15, quad, acc);

#pragma unroll
    for (int i = 0; i < 4; ++i) {
      int r = row0 + wm * 64 + i * 16 + l15;
      if (r >= n) continue;
#pragma unroll
      for (int j = 0; j < 4; ++j) {
        int c0 = wn * 64 + j * 16 + quad * 4;
        float4 bb = *(const float4*)(bb1 + c0);
        float v0 = fmaxf(acc[i][j][0] + bb.x, 0.f);
        float v1 = fmaxf(acc[i][j][1] + bb.y, 0.f);
        float v2 = fmaxf(acc[i][j][2] + bb.z, 0.f);
        float v3 = fmaxf(acc[i][j][3] + bb.w, 0.f);
        uint2 o; o.x = pack2(v0, v1); o.y = pack2(v2, v3);
        *(uint2*)(D + (size_t)r * 128 + c0) = o;
      }
    }
  }
}

// out = relu(C·Wm0 + D·Wm1 + G2·Wm2 + bm)·Wo1^T + bo + Pout  (A3 in LDS only)
__global__ __launch_bounds__(256, 2) void wm_final_kernel(
    const unsigned short* __restrict__ C, const unsigned short* __restrict__ D,
    const unsigned short* __restrict__ G2,
    const unsigned short* __restrict__ Wm, const float* __restrict__ bm,
    const unsigned short* __restrict__ Wo1, const float* __restrict__ bo,
    const float* __restrict__ Pout, float* __restrict__ out, int n)
{
  __shared__ unsigned short Xs[128 * LDXP];
  const int tid = threadIdx.x;
  const int lane = tid & 63;
  const int wave = tid >> 6;
  const int wm_ = wave >> 1;
  const int wn = wave & 1;
  const int l15 = lane & 15;
  const int quad = lane >> 4;
  const int row0 = blockIdx.x * 128;
  const int c8 = (tid & 15) * 8;
  const int rloc = tid >> 4;

  floatx4 acc[4][4];
#pragma unroll
  for (int i = 0; i < 4; ++i)
#pragma unroll
    for (int j = 0; j < 4; ++j) acc[i][j] = (floatx4){0.f, 0.f, 0.f, 0.f};

  const unsigned short* Xp[3] = {C, D, G2};
#pragma unroll
  for (int s = 0; s < 3; ++s) {
    if (s) __syncthreads();
    stage_bf16(Xp[s], Xs, row0, n, rloc, c8);
    __syncthreads();
    mfma_phase<4>(Wm + s * 128, 384, Xs, wm_, wn, l15, quad, acc);
  }
  __syncthreads();   // all K=384 reads done before A3 overwrite

  // A3 = relu(acc + bm) -> Xs (bf16)
#pragma unroll
  for (int i = 0; i < 4; ++i) {
    int r2 = wm_ * 64 + i * 16 + l15;
#pragma unroll
    for (int j = 0; j < 4; ++j) {
      int c2 = wn * 64 + j * 16 + quad * 4;
      float4 bb = *(const float4*)(bm + c2);
      float v0 = fmaxf(acc[i][j][0] + bb.x, 0.f);
      float v1 = fmaxf(acc[i][j][1] + bb.y, 0.f);
      float v2 = fmaxf(acc[i][j][2] + bb.z, 0.f);
      float v3 = fmaxf(acc[i][j][3] + bb.w, 0.f);
      uint2 o; o.x = pack2(v0, v1); o.y = pack2(v2, v3);
      *(uint2*)(Xs + r2 * LDXP + c2) = o;
    }
  }
  __syncthreads();

  floatx4 acc2[4][2];
#pragma unroll
  for (int i = 0; i < 4; ++i)
#pragma unroll
    for (int j = 0; j < 2; ++j) acc2[i][j] = (floatx4){0.f, 0.f, 0.f, 0.f};
  mfma_phase<2>(Wo1, 128, Xs, wm_, wn, l15, quad, acc2);

#pragma unroll
  for (int i = 0; i < 4; ++i) {
    int r = row0 + wm_ * 64 + i * 16 + l15;
    if (r >= n) continue;
#pragma unroll
    for (int j = 0; j < 2; ++j) {
      int c0 = wn * 32 + j * 16 + quad * 4;
      float4 bb = *(const float4*)(bo + c0);
      float4 pv = *(const float4*)(Pout + (size_t)r * 64 + c0);
      float4 o;
      o.x = acc2[i][j][0] + bb.x + pv.x;
      o.y = acc2[i][j][1] + bb.y + pv.y;
      o.z = acc2[i][j][2] + bb.z + pv.z;
      o.w = acc2[i][j][3] + bb.w + pv.w;
      *(float4*)(out + (size_t)r * 64 + c0) = o;
    }
  }
}

extern "C" void kernel_launch(void* const* d_in, const int* in_sizes, int n_in,
                              void* d_out, int out_size, void* d_ws, size_t ws_size,
                              hipStream_t stream)
{
  const float* x     = (const float*)d_in[0];
  const int*   row_a = (const int*)d_in[1];
  const int*   col_a = (const int*)d_in[2];
  const float* val_a = (const float*)d_in[3];
  const int*   row_b = (const int*)d_in[4];
  const int*   col_b = (const int*)d_in[5];
  const float* val_b = (const float*)d_in[6];
  const float* Wa0 = (const float*)d_in[7];  const float* ba0 = (const float*)d_in[8];
  const float* Wa1 = (const float*)d_in[9];  const float* ba1 = (const float*)d_in[10];
  const float* Wb0 = (const float*)d_in[11]; const float* bb0 = (const float*)d_in[12];
  const float* Wb1 = (const float*)d_in[13]; const float* bb1 = (const float*)d_in[14];
  const float* Wm  = (const float*)d_in[15]; const float* bm  = (const float*)d_in[16];
  const float* Wo  = (const float*)d_in[17]; const float* bo  = (const float*)d_in[18];
  float* out = (float*)d_out;

  const int n = in_sizes[0] / 128;   // 50000
  const int E = in_sizes[1];         // 800000

  char* ws = (char*)d_ws;
  size_t off = 0;
  auto alloc = [&](size_t bytes) {
    void* p = ws + off;
    off = (off + bytes + 255) & ~(size_t)255;
    return p;
  };
  int* rpa = (int*)alloc((size_t)(n + 1) * sizeof(int));
  int* rpb = (int*)alloc((size_t)(n + 1) * sizeof(int));
  unsigned short* Wcat = (unsigned short*)alloc(131072 * sizeof(unsigned short));
  const size_t slab = (size_t)n * 128 * sizeof(unsigned short);
  unsigned short* A  = (unsigned short*)alloc(slab);   // relu(x Wa0 + ba0)
  unsigned short* C  = (unsigned short*)alloc(slab);   // g0
  unsigned short* B  = (unsigned short*)alloc(slab);   // graph-a sp1 out / g2
  unsigned short* B2 = (unsigned short*)alloc(slab);   // graph-b sp1 out
  unsigned short* D  = (unsigned short*)alloc(slab);   // g1
  unsigned short* Q  = (unsigned short*)alloc((size_t)n * 64 * sizeof(unsigned short));
  float* Pout = (float*)alloc((size_t)n * 64 * sizeof(float)); // x_a @ Wo0^T

  const unsigned short* Wa0b = Wcat;
  const unsigned short* Wa1b = Wcat + 16384;
  const unsigned short* Wb0b = Wcat + 32768;
  const unsigned short* Wb1b = Wcat + 49152;
  const unsigned short* Wmb  = Wcat + 65536;   // [128, 384]
  const unsigned short* Wo0b = Wcat + 114688;
  const unsigned short* Wo1b = Wcat + 122880;

  dim3 blk(256);
  dim3 g_setup((n + 1 + 255) / 256, 3);
  dim3 g_lin((n + 127) / 128);
  dim3 g_cg((n + 127) / 128, 2);
  dim3 g_sp2((n + 31) / 32, 2);      // 32 rows/block for all spmm variants

  setup_kernel<<<g_setup, blk, 0, stream>>>(row_a, row_b, E, n, rpa, rpb,
                                            Wa0, Wa1, Wb0, Wb1, Wm, Wo, Wcat);

  // A = relu(x Wa0^T + ba0), C = relu(x Wb0^T + bb0)
  gemm_dual_f32_kernel<<<g_lin, blk, 0, stream>>>(x, Wa0b, Wb0b, ba0, bb0, A, C, n);

  // spmm_a(A->B) || spmm_b(C->B2)   (2-phase feature-split gathers)
  spmm_dual128_kernel<<<g_sp2, blk, 0, stream>>>(
      rpa, col_a, val_a, A, B,
      rpb, col_b, val_b, C, B2, n);

  // chain: Q = relu(B Wa1^T + ba1) Wo0^T  ||  g1: D = relu(B2 Wb1^T + bb1)
  chain_g1_kernel<<<g_cg, blk, 0, stream>>>(
      B, Wa1b, ba1, Wo0b, Q,
      B2, Wb1b, bb1, D, n);

  // g2 = spmm_b(D) -> B (2-phase)  ||  Pout = spmm_a(Q) (64-wide)
  spmm_mixed_kernel<<<g_sp2, blk, 0, stream>>>(
      rpb, col_b, val_b, D, B,
      rpa, col_a, val_a, Q, Pout, n);

  // out = relu(g0 Wm0 + g1 Wm1 + g2 Wm2 + bm) Wo1^T + bo + Pout
  wm_final_kernel<<<g_lin, blk, 0, stream>>>(
      C, D, B, Wmb, bm, Wo1b, bo, Pout, out, n);
}